// Round 5
// baseline (494.507 us; speedup 1.0000x reference)
//
#include <hip/hip_runtime.h>

#define D 768
#define B 32
#define L 512
#define M 128
#define NNODES 3072
#define NEDGES 24576

using bf16x8 = __attribute__((ext_vector_type(8))) short;
using f32x4  = __attribute__((ext_vector_type(4))) float;

__device__ __forceinline__ float bf2f(unsigned short u) {
  union { unsigned int i; float f; } v; v.i = ((unsigned int)u) << 16; return v.f;
}
__device__ __forceinline__ unsigned short f2bf(float f) {
  union { float f; unsigned int i; } v; v.f = f;
  unsigned int x = v.i;
  return (unsigned short)((x + 0x7FFFu + ((x >> 16) & 1u)) >> 16);
}
__device__ __forceinline__ float ldf(const void* p, size_t i, int f32) {
  return f32 ? ((const float*)p)[i] : bf2f(((const unsigned short*)p)[i]);
}
__device__ __forceinline__ int ldi(const void* p, size_t i, int w64) {
  return w64 ? (int)((const long long*)p)[i] : ((const int*)p)[i];
}
__device__ __forceinline__ f32x4 mfma16(bf16x8 a, bf16x8 b, f32x4 c) {
  return __builtin_amdgcn_mfma_f32_16x16x32_bf16(a, b, c, 0, 0, 0);
}
__device__ __forceinline__ void gl_lds(const unsigned short* gsrc, unsigned short* lbase,
                                       int lane) {
  __builtin_amdgcn_global_load_lds(
      (const __attribute__((address_space(1))) unsigned int*)(gsrc + lane * 8),
      (__attribute__((address_space(3))) unsigned int*)lbase, 16, 0, 0);
}

// Packed layout, element (node n, feat k):
//   PK[n>>4][k>>5][((k&31)>>3)*16 + (n&15)][k&7], strides {12288,512,8,1} ushorts.
__device__ __forceinline__ float pk_read(const unsigned short* P, int p, int l, int d) {
  return bf2f(P[(((size_t)(p * 24 + (d >> 5))) << 9) + ((((d & 31) >> 3) << 4) + l) * 8 + (d & 7)]);
}

__device__ __forceinline__ void fma8(float* acc, float w, uint4 v) {
  unsigned xs[4] = {v.x, v.y, v.z, v.w};
#pragma unroll
  for (int j = 0; j < 4; ++j) {
    acc[2 * j]     += w * bf2f((unsigned short)(xs[j] & 0xFFFFu));
    acc[2 * j + 1] += w * bf2f((unsigned short)(xs[j] >> 16));
  }
}

__device__ __forceinline__ void acc12(float* a, const uint2* u) {
#pragma unroll
  for (int j = 0; j < 3; ++j) {
    a[j * 4 + 0] += bf2f((unsigned short)(u[j].x & 0xFFFFu));
    a[j * 4 + 1] += bf2f((unsigned short)(u[j].x >> 16));
    a[j * 4 + 2] += bf2f((unsigned short)(u[j].y & 0xFFFFu));
    a[j * 4 + 3] += bf2f((unsigned short)(u[j].y >> 16));
  }
}

// ================= device role bodies =================

// Pack row-major source into packed layout (single destination), phase-split loads.
__device__ void d_pack_in(const void* src, unsigned short* dst, int p, int tid, int f) {
  unsigned short* pb = dst + (size_t)p * 12288;
  uint4 qv[6];
  if (f) {
    float4 v0[6], v1[6];
#pragma unroll
    for (int j = 0; j < 6; ++j) {
      int odx = j * 256 + tid;
      int kk = odx >> 6, lanep = odx & 63;
      size_t sbase = (size_t)(p * 16 + (lanep & 15)) * 768 + kk * 32 + ((lanep >> 4) << 3);
      const float* sp = (const float*)src + sbase;
      v0[j] = *(const float4*)sp;
      v1[j] = *(const float4*)(sp + 4);
    }
#pragma unroll
    for (int j = 0; j < 6; ++j) {
      union { unsigned short v[8]; uint4 q; } u;
      u.v[0] = f2bf(v0[j].x); u.v[1] = f2bf(v0[j].y); u.v[2] = f2bf(v0[j].z); u.v[3] = f2bf(v0[j].w);
      u.v[4] = f2bf(v1[j].x); u.v[5] = f2bf(v1[j].y); u.v[6] = f2bf(v1[j].z); u.v[7] = f2bf(v1[j].w);
      qv[j] = u.q;
    }
  } else {
#pragma unroll
    for (int j = 0; j < 6; ++j) {
      int odx = j * 256 + tid;
      int kk = odx >> 6, lanep = odx & 63;
      size_t sbase = (size_t)(p * 16 + (lanep & 15)) * 768 + kk * 32 + ((lanep >> 4) << 3);
      qv[j] = *(const uint4*)((const unsigned short*)src + sbase);
    }
  }
#pragma unroll
  for (int j = 0; j < 6; ++j)
    *(uint4*)&pb[(size_t)(j * 256 + tid) * 8] = qv[j];
}

// LDS-free wpack: packed (pG,kk,lane,e) = W[kk*32+(lane>>4)*8+e][pG*16+(lane&15)].
__device__ void d_wpack(const void* Ws, const void* Wn, const void* Aw, int f,
                        unsigned short* WsPk, unsigned short* WnPk, unsigned short* AwPk,
                        int r0, int tid) {
  int z = r0 / 288, rem = r0 % 288;
  int nblk = rem % 12, kk = rem / 12;
  const void* src; unsigned short* dst; size_t zoff;
  if (z < 3)      { src = Ws; zoff = (size_t)z * D * D;       dst = WsPk + zoff; }
  else if (z < 6) { src = Wn; zoff = (size_t)(z - 3) * D * D; dst = WnPk + zoff; }
  else            { src = Aw; zoff = 0;                       dst = AwPk; }
  int pl = tid >> 6, lane = tid & 63;
  int pG = nblk * 4 + pl;
  int k0 = kk * 32 + ((lane >> 4) << 3);
  int n  = nblk * 64 + pl * 16 + (lane & 15);
  union { unsigned short v[8]; uint4 q; } u;
  if (f) {
    const float* sp = (const float*)src + zoff + (size_t)k0 * D + n;
#pragma unroll
    for (int e = 0; e < 8; ++e) u.v[e] = f2bf(sp[(size_t)e * D]);
  } else {
    const unsigned short* sp = (const unsigned short*)src + zoff + (size_t)k0 * D + n;
#pragma unroll
    for (int e = 0; e < 8; ++e) u.v[e] = sp[(size_t)e * D];
  }
  *(uint4*)&dst[(((size_t)(pG * 24 + kk)) << 9) + lane * 8] = u.q;
}

// count: edge atomics stay; gcnt uses sorted-run ballot (batch is sorted).
__device__ void d_count(const void* edst, const void* batch, int w,
                        int* cnt, int* gcnt, int i) {
  if (i < NEDGES) atomicAdd(&cnt[ldi(edst, i, w)], 1);
  if (i < NNODES) {
    int b = ldi(batch, i, w);
    int lane = i & 63;
    int prev = __shfl_up(b, 1);
    bool first = (lane == 0) || (prev != b);
    unsigned long long bm = __ballot(first ? 1 : 0);
    if (first) {
      unsigned long long higher = (lane < 63) ? (bm >> (lane + 1)) : 0ULL;
      int next = higher ? (lane + __ffsll((long long)higher)) : 64;
      atomicAdd(&gcnt[b], next - lane);
    }
  }
}

// msg: gathers source rows from PACKED Px, writes packed Mpk. 2-row interleave.
__device__ void d_msg(const unsigned short* Px, const int* cnt, const int* rowstart,
                      const int* csr, unsigned short* Mpk, int p, int tid) {
  int w = tid >> 6, lane = tid & 63;
  unsigned short* pb = Mpk + (size_t)p * 12288;
  int koff[3];
#pragma unroll
  for (int j = 0; j < 3; ++j) {
    int k0 = (lane + j * 64) * 4;
    koff[j] = (k0 >> 5) * 512 + ((k0 >> 3) & 3) * 128 + (k0 & 7);
  }
#pragma unroll
  for (int i = 0; i < 4; i += 2) {
    int rA = w * 4 + i, rB = rA + 1;
    int nA = p * 16 + rA, nB = p * 16 + rB;
    int degA = cnt[nA], baseA = rowstart[nA];
    int degB = cnt[nB], baseB = rowstart[nB];
    float aA[12], aB[12];
#pragma unroll
    for (int j = 0; j < 12; ++j) { aA[j] = 0.f; aB[j] = 0.f; }
    int dmax = degA > degB ? degA : degB;
    for (int e = 0; e < dmax; ++e) {
      uint2 uA[3], uB[3];
      if (e < degA) {
        int n = csr[baseA + e];
        const unsigned short* gb = Px + (size_t)(n >> 4) * 12288 + (n & 15) * 8;
        uA[0] = *(const uint2*)(gb + koff[0]);
        uA[1] = *(const uint2*)(gb + koff[1]);
        uA[2] = *(const uint2*)(gb + koff[2]);
      }
      if (e < degB) {
        int n = csr[baseB + e];
        const unsigned short* gb = Px + (size_t)(n >> 4) * 12288 + (n & 15) * 8;
        uB[0] = *(const uint2*)(gb + koff[0]);
        uB[1] = *(const uint2*)(gb + koff[1]);
        uB[2] = *(const uint2*)(gb + koff[2]);
      }
      if (e < degA) acc12(aA, uA);
      if (e < degB) acc12(aB, uB);
    }
    float invA = 1.0f / (float)(degA > 1 ? degA : 1);
    float invB = 1.0f / (float)(degB > 1 ? degB : 1);
#pragma unroll
    for (int j = 0; j < 3; ++j) {
      uint2 wA, wB;
      wA.x = (unsigned int)f2bf(aA[j * 4 + 0] * invA)
           | ((unsigned int)f2bf(aA[j * 4 + 1] * invA) << 16);
      wA.y = (unsigned int)f2bf(aA[j * 4 + 2] * invA)
           | ((unsigned int)f2bf(aA[j * 4 + 3] * invA) << 16);
      wB.x = (unsigned int)f2bf(aB[j * 4 + 0] * invB)
           | ((unsigned int)f2bf(aB[j * 4 + 1] * invB) << 16);
      wB.y = (unsigned int)f2bf(aB[j * 4 + 2] * invB)
           | ((unsigned int)f2bf(aB[j * 4 + 3] * invB) << 16);
      *(uint2*)&pb[koff[j] + rA * 8] = wA;
      *(uint2*)&pb[koff[j] + rB * 8] = wB;
    }
  }
}

// 48KB: 6 buffers x 4096 ushorts (8KB), 1-kk rounds, depth-5 counted vmcnt(8).
// Output written in PACKED layout directly.
__device__ void d_gemm(const unsigned short* Xpk, const unsigned short* Mpk,
                       const unsigned short* WsPk, const unsigned short* WnPk,
                       const void* bias, size_t bias_off, int f,
                       unsigned short* Ypk, int bx, int by, int tid, char* smem) {
  unsigned short* lds = (unsigned short*)smem;   // 6 * 4096 ushorts = 48KB
  int wave = tid >> 6, lane = tid & 63;
  int q = lane >> 4, t = lane & 15;
  int wm = wave >> 1, wn = wave & 1;
  int pa = bx * 4, pbp = by * 4;
  f32x4 acc[2][2];
#pragma unroll
  for (int mi = 0; mi < 2; ++mi)
#pragma unroll
    for (int ni = 0; ni < 2; ++ni)
      acc[mi][ni] = (f32x4){0.f, 0.f, 0.f, 0.f};
  int c0 = wave * 2;
  int pan0 = (wave < 2) ? (pa + c0) : (pbp + c0 - 4);
  auto issue = [&](int s) {
    int h = (s >= 24) ? 1 : 0;
    const unsigned short* P = (wave < 2) ? (h ? Mpk : Xpk) : (h ? WnPk : WsPk);
    int kk = s - h * 24;
    unsigned short* dbuf = &lds[(s % 6) * 4096 + c0 * 512];
    gl_lds(P + (((size_t)(pan0 * 24 + kk)) << 9), dbuf, lane);
    gl_lds(P + (((size_t)((pan0 + 1) * 24 + kk)) << 9), dbuf + 512, lane);
  };
#pragma unroll
  for (int s = 0; s < 5; ++s) issue(s);
  for (int r = 0; r < 48; ++r) {
    if (r < 44) asm volatile("s_waitcnt vmcnt(8)" ::: "memory");
    else        asm volatile("s_waitcnt vmcnt(0)" ::: "memory");
    __builtin_amdgcn_s_barrier();
    asm volatile("" ::: "memory");
    if (r + 5 < 48) issue(r + 5);
    const unsigned short* bs = &lds[(r % 6) * 4096];
    bf16x8 a0 = *(const bf16x8*)&bs[(wm * 2 + 0) * 512 + lane * 8];
    bf16x8 a1 = *(const bf16x8*)&bs[(wm * 2 + 1) * 512 + lane * 8];
    bf16x8 b0 = *(const bf16x8*)&bs[(4 + wn * 2 + 0) * 512 + lane * 8];
    bf16x8 b1 = *(const bf16x8*)&bs[(4 + wn * 2 + 1) * 512 + lane * 8];
    acc[0][0] = mfma16(a0, b0, acc[0][0]);
    acc[0][1] = mfma16(a0, b1, acc[0][1]);
    acc[1][0] = mfma16(a1, b0, acc[1][0]);
    acc[1][1] = mfma16(a1, b1, acc[1][1]);
    asm volatile("" ::: "memory");
  }
#pragma unroll
  for (int ni = 0; ni < 2; ++ni) {
    int col = by * 64 + wn * 32 + ni * 16 + t;
    float bv = ldf(bias, bias_off + col, f);
    int kkc = col >> 5, cq = (col >> 3) & 3, ec = col & 7;
#pragma unroll
    for (int mi = 0; mi < 2; ++mi) {
      int pOut = bx * 4 + wm * 2 + mi;
      unsigned short* ob = Ypk + (size_t)pOut * 12288 + kkc * 512 + ec;
#pragma unroll
      for (int r = 0; r < 4; ++r) {
        float v = acc[mi][ni][r] + bv;
        ob[(cq * 16 + q * 4 + r) * 8] = f2bf(v > 0.f ? v : 0.f);
      }
    }
  }
}

// xp: gather padded-node rows from packed PkN; write XpPk packed (+ optional xgacc).
__device__ void d_xp(const unsigned short* PkN, const void* pidx, int w64,
                     const int* gcnt, unsigned short* XpPk,
                     float* xgacc, int p, int tid, char* smem) {
  unsigned short* rows = (unsigned short*)smem;   // 16*776 ushorts
  int r = tid >> 4, c16 = tid & 15;
  int bm = p * 16 + r;
  int b = bm >> 7, m = bm & 127;
  int nb = gcnt[b];
  uint4* dl = (uint4*)&rows[r * 776];
  uint4 v[6];
  if (m < nb) {
    int n = ldi(pidx, bm, w64);
    const unsigned short* base = PkN + (size_t)(n >> 4) * 12288 + (n & 15) * 8;
#pragma unroll
    for (int j = 0; j < 6; ++j) {
      int mg = c16 + j * 16;
      v[j] = *(const uint4*)(base + (mg >> 2) * 512 + (mg & 3) * 128);
    }
  } else {
    uint4 z = {0u, 0u, 0u, 0u};
#pragma unroll
    for (int j = 0; j < 6; ++j) v[j] = z;
  }
#pragma unroll
  for (int j = 0; j < 6; ++j) dl[c16 + j * 16] = v[j];
  __syncthreads();
  unsigned short* pb = XpPk + (size_t)p * 12288;
#pragma unroll
  for (int j = 0; j < 6; ++j) {
    int odx = j * 256 + tid;
    int kk = odx >> 6, lanep = odx & 63;
    int rr = lanep & 15, cg = lanep >> 4;
    int cc = kk * 4 + cg;
    uint4 vv = *(const uint4*)&rows[rr * 776 + cc * 8];
    *(uint4*)&pb[odx * 8] = vv;
  }
  if (xgacc) {
    int bb = p >> 3;
#pragma unroll
    for (int j = 0; j < 3; ++j) {
      int d = j * 256 + tid;
      float s = 0.f;
#pragma unroll
      for (int rr = 0; rr < 16; ++rr) s += bf2f(rows[rr * 776 + d]);
      atomicAdd(&xgacc[(size_t)bb * D + d], s);
    }
  }
}

// 48KB: 6 buffers, 24 1-kk rounds, depth-5 counted vmcnt(8).
__device__ void d_scores(const unsigned short* XpPk, const unsigned short* Tpk,
                         float* S, int bx, int by, int bz, int tid, char* smem) {
  unsigned short* lds = (unsigned short*)smem;   // 6 * 4096 ushorts = 48KB
  int wave = tid >> 6, lane = tid & 63;
  int q = lane >> 4, t = lane & 15;
  int wm = wave >> 1, wn = wave & 1;
  int pa = bz * 8 + bx * 4;
  int pbp = bz * 32 + by * 4;
  f32x4 acc[2][2];
#pragma unroll
  for (int mi = 0; mi < 2; ++mi)
#pragma unroll
    for (int ni = 0; ni < 2; ++ni)
      acc[mi][ni] = (f32x4){0.f, 0.f, 0.f, 0.f};
  int c0 = wave * 2;
  const unsigned short* P = (wave < 2) ? XpPk : Tpk;
  int pan0 = (wave < 2) ? (pa + c0) : (pbp + c0 - 4);
  auto issue = [&](int kk) {
    unsigned short* dbuf = &lds[(kk % 6) * 4096 + c0 * 512];
    gl_lds(P + (((size_t)(pan0 * 24 + kk)) << 9), dbuf, lane);
    gl_lds(P + (((size_t)((pan0 + 1) * 24 + kk)) << 9), dbuf + 512, lane);
  };
#pragma unroll
  for (int s = 0; s < 5; ++s) issue(s);
  for (int r = 0; r < 24; ++r) {
    if (r < 20) asm volatile("s_waitcnt vmcnt(8)" ::: "memory");
    else        asm volatile("s_waitcnt vmcnt(0)" ::: "memory");
    __builtin_amdgcn_s_barrier();
    asm volatile("" ::: "memory");
    if (r + 5 < 24) issue(r + 5);
    const unsigned short* bs = &lds[(r % 6) * 4096];
    bf16x8 a0 = *(const bf16x8*)&bs[(wm * 2 + 0) * 512 + lane * 8];
    bf16x8 a1 = *(const bf16x8*)&bs[(wm * 2 + 1) * 512 + lane * 8];
    bf16x8 b0 = *(const bf16x8*)&bs[(4 + wn * 2 + 0) * 512 + lane * 8];
    bf16x8 b1 = *(const bf16x8*)&bs[(4 + wn * 2 + 1) * 512 + lane * 8];
    acc[0][0] = mfma16(a0, b0, acc[0][0]);
    acc[0][1] = mfma16(a0, b1, acc[0][1]);
    acc[1][0] = mfma16(a1, b0, acc[1][0]);
    acc[1][1] = mfma16(a1, b1, acc[1][1]);
    asm volatile("" ::: "memory");
  }
  float* Sb = S + (size_t)bz * M * L;
#pragma unroll
  for (int ni = 0; ni < 2; ++ni) {
    int col = by * 64 + wn * 32 + ni * 16 + t;
#pragma unroll
    for (int mi = 0; mi < 2; ++mi) {
#pragma unroll
      for (int r = 0; r < 4; ++r) {
        int row = bx * 64 + wm * 32 + mi * 16 + q * 4 + r;
        Sb[(size_t)row * L + col] = acc[mi][ni][r];
      }
    }
  }
}

__device__ void d_stats(const float* S, const int* gcnt, float* rmax, float* rsum,
                        float* cmaxv, float* csumv, int bid, int tid, char* smem) {
  if (bid < B * M) {
    float* red = (float*)smem;
    int lane = tid & 63, wv = tid >> 6;
    const float* r = S + (size_t)bid * L;
    float s0 = r[tid], s1 = r[tid + 256];
    float m = fmaxf(s0, s1);
#pragma unroll
    for (int o = 32; o > 0; o >>= 1) m = fmaxf(m, __shfl_down(m, o));
    if (lane == 0) red[wv] = m;
    __syncthreads();
    float bm = fmaxf(fmaxf(red[0], red[1]), fmaxf(red[2], red[3]));
    __syncthreads();
    float e = __expf(s0 - bm) + __expf(s1 - bm);
#pragma unroll
    for (int o = 32; o > 0; o >>= 1) e += __shfl_down(e, o);
    if (lane == 0) red[wv] = e;
    __syncthreads();
    if (tid == 0) { rmax[bid] = bm; rsum[bid] = red[0] + red[1] + red[2] + red[3]; }
  } else {
    float (*pm)[64] = (float(*)[64])smem;
    float (*ps)[64] = (float(*)[64])(smem + 1024);
    int cid = bid - B * M;
    int b = cid >> 3, ly = cid & 7;
    int w = tid >> 6, lane = tid & 63;
    int l = ly * 64 + lane;
    int nb = gcnt[b];
    const float* Sb = S + (size_t)b * M * L;
    int m0 = w * 32, m1 = min(m0 + 32, nb);
    float cm = -1e30f, cs = 0.f;
    for (int m = m0; m < m1; ++m) {
      float s = Sb[(size_t)m * L + l];
      if (s > cm) { cs = cs * __expf(cm - s) + 1.f; cm = s; }
      else cs += __expf(s - cm);
    }
    pm[w][lane] = cm; ps[w][lane] = cs;
    __syncthreads();
    if (w == 0) {
      float CM = -1e30f;
#pragma unroll
      for (int j = 0; j < 4; ++j) CM = fmaxf(CM, pm[j][lane]);
      float CS = 0.f;
#pragma unroll
      for (int j = 0; j < 4; ++j) CS += ps[j][lane] * __expf(pm[j][lane] - CM);
      cmaxv[b * L + l] = CM; csumv[b * L + l] = CS;
    }
  }
}

__device__ void d_cross(const float* S, const float* rmax, const float* rsum,
                        const float* cmaxv, const float* csumv, const int* gcnt,
                        float* wv, float* t2gcol, int bid, int tid, char* smem) {
  if (bid < 256) {
    float* rm = (float*)smem;               // 128
    float* ri = (float*)(smem + 512);       // 128
    float (*pw)[64] = (float(*)[64])(smem + 1024);
    int b = bid >> 3, ly = bid & 7;
    int w = tid >> 6, lane = tid & 63;
    if (tid < M) { rm[tid] = rmax[b * M + tid]; ri[tid] = 1.f / rsum[b * M + tid]; }
    __syncthreads();
    int l = ly * 64 + lane;
    int nb = gcnt[b];
    const float* Sb = S + (size_t)b * M * L;
    int m0 = w * 32, m1 = min(m0 + 32, nb);
    float wp = 0.f;
    for (int m = m0; m < m1; ++m)
      wp += __expf(Sb[(size_t)m * L + l] - rm[m]) * ri[m];
    pw[w][lane] = wp;
    __syncthreads();
    if (w == 0)
      wv[b * L + l] = pw[0][lane] + pw[1][lane] + pw[2][lane] + pw[3][lane];
  } else {
    float* red = (float*)smem;
    int bm = bid - 256;
    int b = bm >> 7, m = bm & 127;
    int lane = tid & 63, w = tid >> 6;
    int nb = gcnt[b];
    float acc = 0.f;
    if (m < nb) {
      const float* r = S + (size_t)bm * L;
      const float* cm = cmaxv + b * L;
      const float* cs = csumv + b * L;
      acc = __expf(r[tid] - cm[tid]) / cs[tid]
          + __expf(r[tid + 256] - cm[tid + 256]) / cs[tid + 256];
    }
#pragma unroll
    for (int o = 32; o > 0; o >>= 1) acc += __shfl_down(acc, o);
    if (lane == 0) red[w] = acc;
    __syncthreads();
    if (tid == 0) t2gcol[bm] = red[0] + red[1] + red[2] + red[3];
  }
}

// pooled: bid = b*10 + seg. seg<8: wv*text (Tpk packed); seg 8..9: t2gcol*xp (XpPk packed).
__device__ void d_pooled(const float* wv, const float* t2gcol, const unsigned short* Tpk,
                         const unsigned short* XpPk, const int* gcnt, float* pooled,
                         int bid, int tid, char* smem) {
  float* lred = (float*)smem;
  float* wbuf = (float*)(smem + 3072);
  int b = bid / 10, seg = bid - b * 10;
  int chunk = tid % 96, half = tid / 96;
  int d = chunk * 8;
  float acc[8];
#pragma unroll
  for (int j = 0; j < 8; ++j) acc[j] = 0.f;
  if (tid < 64) {
    wbuf[tid] = (seg < 8) ? wv[b * L + seg * 64 + tid]
                          : t2gcol[b * M + (seg - 8) * 64 + tid];
  }
  __syncthreads();
  if (half < 2) {
    size_t cbase = ((size_t)(d >> 5)) << 9;
    int coff = ((d & 31) >> 3) << 4;
    if (seg < 8) {
      int pbase = b * 32 + seg * 4;
      for (int i = 0; i < 32; ++i) {
        int l = half * 32 + i;
        const unsigned short* src =
            Tpk + (size_t)(pbase + (l >> 4)) * 12288 + cbase + (size_t)(coff + (l & 15)) * 8;
        fma8(acc, wbuf[l], *(const uint4*)src);
      }
    } else {
      const unsigned short* Xb = XpPk + (size_t)b * 8 * 12288;
      int m0 = (seg - 8) * 64;
      for (int i = 0; i < 32; ++i) {
        int mm = half * 32 + i;
        int node = m0 + mm;
        const unsigned short* src =
            Xb + (size_t)(node >> 4) * 12288 + cbase + (size_t)(coff + (node & 15)) * 8;
        fma8(acc, wbuf[mm], *(const uint4*)src);
      }
    }
  }
  if (half == 1) {
#pragma unroll
    for (int j = 0; j < 8; ++j) lred[chunk * 8 + j] = acc[j];
  }
  __syncthreads();
  if (half == 0) {
    float inv = 1.f / ((float)gcnt[b] + 512.f);
#pragma unroll
    for (int j = 0; j < 8; ++j)
      atomicAdd(&pooled[(size_t)b * D + d + j], (acc[j] + lred[chunk * 8 + j]) * inv);
  }
}

__device__ void d_atom(const float* xgacc, const int* gcnt, const unsigned short* AwPk,
                       float* gpre, int bid, int tid) {
  int w = tid >> 6, lane = tid & 63;
  int q = lane >> 4, t = lane & 15;
  int nbase = bid * 64 + w * 16;
  int pb = nbase >> 4;
  int n0 = gcnt[t], n1 = gcnt[16 + t];
  float inv0 = 1.f / (float)(n0 > 1 ? n0 : 1);
  float inv1 = 1.f / (float)(n1 > 1 ? n1 : 1);
  f32x4 acc[2];
  acc[0] = (f32x4){0.f, 0.f, 0.f, 0.f};
  acc[1] = (f32x4){0.f, 0.f, 0.f, 0.f};
  for (int kk = 0; kk < 24; ++kk) {
    const float* s0 = xgacc + (size_t)t * D + kk * 32 + q * 8;
    const float* s1 = xgacc + (size_t)(16 + t) * D + kk * 32 + q * 8;
    union { unsigned short v[8]; bf16x8 f; } a0, a1;
#pragma unroll
    for (int j = 0; j < 8; ++j) { a0.v[j] = f2bf(s0[j] * inv0); a1.v[j] = f2bf(s1[j] * inv1); }
    bf16x8 bv = *(const bf16x8*)(AwPk + (((size_t)(pb * 24 + kk)) << 9) + (lane << 3));
    acc[0] = mfma16(a0.f, bv, acc[0]);
    acc[1] = mfma16(a1.f, bv, acc[1]);
  }
#pragma unroll
  for (int mi = 0; mi < 2; ++mi)
#pragma unroll
    for (int r = 0; r < 4; ++r) {
      int row = mi * 16 + q * 4 + r;
      gpre[(size_t)row * D + nbase + t] = acc[mi][r];
    }
}

// ================= global kernels =================

__global__ void k_init(int* cnt, int* cursor, int* gcnt, float* pooled, float* xgacc,
                       const unsigned short* __restrict__ t,
                       const unsigned int* __restrict__ e, int* __restrict__ flags) {
  int i = blockIdx.x * 256 + threadIdx.x;
  if (i < NNODES) { cnt[i] = 0; cursor[i] = 0; }
  if (i < B) gcnt[i] = 0;
  if (i < B * D) { pooled[i] = 0.f; xgacc[i] = 0.f; }
  if (blockIdx.x == 0) {
    __shared__ int r0[256];
    __shared__ unsigned r1[256];
    int tid = threadIdx.x;
    int bad = 0;
    for (int j = tid; j < 8192; j += 256) {
      unsigned short u = t[2 * j];
      unsigned ex = (u >> 7) & 0xFF;
      if (ex >= 0xC0) bad = 1;
    }
    unsigned o = 0;
    for (int j = tid; j < NEDGES / 2; j += 256) o |= e[2 * j + 1];
    r0[tid] = bad; r1[tid] = o;
    __syncthreads();
    for (int s = 128; s > 0; s >>= 1) {
      if (tid < s) { r0[tid] |= r0[tid + s]; r1[tid] |= r1[tid + s]; }
      __syncthreads();
    }
    if (tid == 0) { flags[0] = r0[0]; flags[1] = (r1[0] == 0) ? 1 : 0; }
  }
}

// pack_in x (0..191) + pack_in text (192..1215) + wpack (1216..3231) + count (3232..3327)
__global__ __launch_bounds__(256) void k_setup2(
    const void* x_in, unsigned short* Pk0,
    const void* text, unsigned short* Tpk,
    const void* Ws, const void* Wn, const void* Aw,
    unsigned short* WsPk, unsigned short* WnPk, unsigned short* AwPk,
    const void* edst, const void* batch, int* cnt, int* gcnt,
    const int* __restrict__ flags) {
  int bid = blockIdx.x, tid = threadIdx.x;
  if (bid < 1216) {
    int f = flags[0];
    if (bid < NNODES / 16) d_pack_in(x_in, Pk0, bid, tid, f);
    else d_pack_in(text, Tpk, bid - NNODES / 16, tid, f);
  } else if (bid < 3232) {
    d_wpack(Ws, Wn, Aw, flags[0], WsPk, WnPk, AwPk, bid - 1216, tid);
  } else {
    d_count(edst, batch, flags[1], cnt, gcnt, (bid - 3232) * 256 + tid);
  }
}

__global__ void k_scan(const int* __restrict__ cnt, int* __restrict__ rowstart) {
  __shared__ int a[NNODES], b[NNODES];
  int tid = threadIdx.x;
  for (int i = tid; i < NNODES; i += 1024) a[i] = cnt[i];
  __syncthreads();
  int* s = a; int* d = b;
  for (int off = 1; off < NNODES; off <<= 1) {
    for (int i = tid; i < NNODES; i += 1024)
      d[i] = s[i] + (i >= off ? s[i - off] : 0);
    __syncthreads();
    int* t = s; s = d; d = t;
  }
  for (int i = tid; i < NNODES; i += 1024) rowstart[i + 1] = s[i];
  if (tid == 0) rowstart[0] = 0;
}

__global__ void k_scatter(const void* __restrict__ esrc, const void* __restrict__ edst,
                          const int* __restrict__ flags, const int* __restrict__ rowstart,
                          int* __restrict__ cursor, int* __restrict__ csr) {
  int w = flags[1];
  int i = blockIdx.x * 256 + threadIdx.x;
  if (i < NEDGES) {
    int dd = ldi(edst, i, w);
    int pos = atomicAdd(&cursor[dd], 1);
    csr[rowstart[dd] + pos] = ldi(esrc, i, w);
  }
}

__global__ __launch_bounds__(256) void k_msgp(
    const unsigned short* Px, const int* cnt, const int* rowstart, const int* csr,
    unsigned short* Mpk) {
  d_msg(Px, cnt, rowstart, csr, Mpk, blockIdx.x, threadIdx.x);
}

// XCD-bijective swizzles (grid%8==0 in both uses).
__device__ __forceinline__ void gemm_map(int g, int& bx, int& by) {
  int gs = (g % 8) * 72 + g / 8;   // 576 = 8*72
  bx = gs / 12; by = gs % 12;
}
__device__ __forceinline__ void sc_map(int g, int& bx, int& by, int& bz) {
  int gs = (g % 8) * 64 + g / 8;   // 512 = 8*64
  bx = gs & 1; by = (gs >> 1) & 7; bz = gs >> 4;
}

__global__ __launch_bounds__(256) void k_gemm(
    const unsigned short* Apk, const unsigned short* Mpk,
    const unsigned short* WsPk, const unsigned short* WnPk,
    const void* bias, unsigned long bias_off, const int* flags, unsigned short* Ypk) {
  extern __shared__ char smem[];
  int bx, by; gemm_map(blockIdx.x, bx, by);
  d_gemm(Apk, Mpk, WsPk, WnPk, bias, bias_off, flags[0], Ypk, bx, by,
         threadIdx.x, smem);
}

// xp only (256 blocks).
__global__ __launch_bounds__(256) void k_postg(
    const unsigned short* PkN, const void* pidx, const int* flags, const int* gcnt,
    unsigned short* XpPk, float* xgacc) {
  extern __shared__ char smem[];
  d_xp(PkN, pidx, flags[1], gcnt, XpPk, xgacc, blockIdx.x, threadIdx.x, smem);
}

// scores (0..511) + msg(next) (512..512+msgN-1)
__global__ __launch_bounds__(256) void k_scmsg(
    const unsigned short* XpPk, const unsigned short* Tpk, float* S,
    int msgN, const unsigned short* Px, const int* cnt, const int* rowstart,
    const int* csr, unsigned short* Mpk) {
  extern __shared__ char smem[];
  int bid = blockIdx.x, tid = threadIdx.x;
  if (bid < 512) {
    int bx, by, bz; sc_map(bid, bx, by, bz);
    d_scores(XpPk, Tpk, S, bx, by, bz, tid, smem);
  } else d_msg(Px, cnt, rowstart, csr, Mpk, bid - 512, tid);
}

// stats (0..4351) + gemm(next) (4352..)
__global__ __launch_bounds__(256) void k_stgemm(
    const float* S, const int* gcnt, float* rmax, float* rsum, float* cmaxv, float* csumv,
    int gemmN, const unsigned short* Apk, const unsigned short* Mpk,
    const unsigned short* WsPk, const unsigned short* WnPk,
    const void* bias, unsigned long bias_off, const int* flags, unsigned short* Ypk) {
  extern __shared__ char smem[];
  int bid = blockIdx.x, tid = threadIdx.x;
  if (bid < 4352) d_stats(S, gcnt, rmax, rsum, cmaxv, csumv, bid, tid, smem);
  else {
    int bx, by; gemm_map(bid - 4352, bx, by);
    d_gemm(Apk, Mpk, WsPk, WnPk, bias, bias_off, flags[0], Ypk, bx, by, tid, smem);
  }
}

// cross (0..4351) + xp(next) (4352..4352+xpN-1)
__global__ __launch_bounds__(256) void k_crpostg(
    const float* S, const float* rmax, const float* rsum, const float* cmaxv,
    const float* csumv, const int* gcnt, float* wv, float* t2gcol,
    int xpN, const unsigned short* PkN, const void* pidx, const int* flags,
    unsigned short* XpPk, float* xgacc) {
  extern __shared__ char smem[];
  int bid = blockIdx.x, tid = threadIdx.x;
  if (bid < 4352) d_cross(S, rmax, rsum, cmaxv, csumv, gcnt, wv, t2gcol, bid, tid, smem);
  else d_xp(PkN, pidx, flags[1], gcnt, XpPk, xgacc, bid - 4352, tid, smem);
}

// pooled (0..319) + scores(next) (320..320+scN-1) + msg (msgN) + atom (atomN).
__global__ __launch_bounds__(256) void k_plscmsg(
    const float* wv, const float* t2gcol, const unsigned short* Tpk,
    const unsigned short* XpPkL, const int* gcnt, float* pooled,
    int scN, const unsigned short* XpPk, float* S,
    int msgN, const unsigned short* Px, const int* cnt, const int* rowstart,
    const int* csr, unsigned short* Mpk,
    int atomN, const float* xgacc, const unsigned short* AwPk, float* gpre) {
  extern __shared__ char smem[];
  int bid = blockIdx.x, tid = threadIdx.x;
  if (bid < 320) { d_pooled(wv, t2gcol, Tpk, XpPkL, gcnt, pooled, bid, tid, smem); return; }
  int r = bid - 320;
  if (r < scN) {
    int bx, by, bz; sc_map(r, bx, by, bz);
    d_scores(XpPk, Tpk, S, bx, by, bz, tid, smem); return;
  }
  r -= scN;
  if (r < msgN) { d_msg(Px, cnt, rowstart, csr, Mpk, r, tid); return; }
  d_atom(xgacc, gcnt, AwPk, gpre, r - msgN, tid);
}

__global__ __launch_bounds__(256) void k_final(
    const unsigned short* __restrict__ Tpk, const float* __restrict__ gpre,
    const float* __restrict__ pooled, const void* __restrict__ ab,
    const void* __restrict__ dmask, const void* __restrict__ gmask,
    const void* __restrict__ remb, const int* __restrict__ flags,
    void* __restrict__ out) {
  int f = flags[0];
  int b = blockIdx.x, tid = threadIdx.x;
  float dm = ldf(dmask, b, f);
  float gm = ldf(gmask, b, f);
  float dg = dm * gm;
  size_t base = (size_t)b * 2304;
#pragma unroll
  for (int j = 0; j < 3; ++j) {
    int d = tid + j * 256;
    float z = ldf(remb, d, f);
    float tv = pk_read(Tpk, b * 32, 0, d);
    float o0 = tv * dm + (1.f - dm) * z;
    float gv = tanhf(gpre[(size_t)b * D + d] + ldf(ab, d, f));
    float o1 = gv * gm + (1.f - gm) * z;
    float p = pooled[(size_t)b * D + d] * (1.f / 3.f);
    float o2 = p * dg + (1.f - dg) * z;
    if (f) {
      float* of = (float*)out;
      of[base + d] = o0; of[base + 768 + d] = o1; of[base + 1536 + d] = o2;
    } else {
      unsigned short* ob = (unsigned short*)out;
      ob[base + d] = f2bf(o0); ob[base + 768 + d] = f2bf(o1); ob[base + 1536 + d] = f2bf(o2);
    }
  }
}

extern "C" void kernel_launch(void* const* d_in, const int* in_sizes, int n_in,
                              void* d_out, int out_size, void* d_ws, size_t ws_size,
                              hipStream_t stream) {
  const void* x_in  = d_in[0];
  const void* text  = d_in[1];
  const void* dmask = d_in[2];
  const void* gmask = d_in[3];
  const void* gws   = d_in[4];
  const void* gwn   = d_in[5];
  const void* gb    = d_in[6];
  const void* aw    = d_in[7];
  const void* ab    = d_in[8];
  const void* remb  = d_in[9];
  const void* batch = d_in[10];
  const void* pidx  = d_in[11];
  const void* esrc  = d_in[13];
  const void* edst  = d_in[14];

  char* wsp = (char*)d_ws;
  size_t off = 0;
  auto carve = [&](size_t bytes) -> void* {
    void* p = wsp + off;
    off += (bytes + 255) & ~(size_t)255;
    return p;
  };
  int* flags = (int*)carve(2 * 4);
  unsigned short* Pk0   = (unsigned short*)carve((size_t)NNODES * D * 2);
  unsigned short* PkN1  = (unsigned short*)carve((size_t)NNODES * D * 2);
  unsigned short* PkN2  = (unsigned short*)carve((size_t)NNODES * D * 2);
  unsigned short* PkN3  = (unsigned short*)carve((size_t)NNODES * D * 2);
  unsigned short* Mpk   = (unsigned short*)carve((size_t)NNODES * D * 2);
  unsigned short* Tpk   = (unsigned short*)carve((size_t)B * L * D * 2);
  unsigned short* WsPk  = (unsigned short*)carve((size_t)3 * D * D * 2);
  unsigned short* WnPk  = (unsigned short*)carve((size_t)3 * D * D * 2);
  unsigned short* AwPk  = (unsigned short*)carve((size_t)D * D * 2);
  unsigned short* XpPkA = (unsigned short*)carve((size_t)B * M * D * 2);
  unsigned short* XpPkB = (unsigned short*)carve((size_t)B * M * D * 2);
  float* xgacc   = (float*)carve((size_t)B * D * 4);
  float* gpre    = (float*)carve((size_t)B * D * 4);
  float* S       = (float*)carve((size_t)B * M * L * 4);
  float* rmax    = (float*)carve((size_t)B * M * 4);
  float* rsum    = (float*)carve((size_t)B * M * 4);
  float* wv      = (float*)carve((size_t)B * L * 4);
  float* cmaxv   = (float*)carve((size_t)B * L * 4);
  float* csumv   = (float*)carve((size_t)B * L * 4);
  float* t2gcol  = (float*)carve((size_t)B * M * 4);
  float* pooled  = (float*)carve((size_t)B * D * 4);
  int* cnt      = (int*)carve((size_t)NNODES * 4);
  int* rowstart = (int*)carve((size_t)(NNODES + 1) * 4);
  int* cursor   = (int*)carve((size_t)NNODES * 4);
  int* gcnt     = (int*)carve((size_t)B * 4);
  int* csr      = (int*)carve((size_t)NEDGES * 4);

  const size_t DD = (size_t)D * D;

  k_init<<<96, 256, 0, stream>>>(cnt, cursor, gcnt, pooled, xgacc,
                                 (const unsigned short*)text, (const unsigned int*)edst, flags);
  k_setup2<<<3328, 256, 0, stream>>>(x_in, Pk0, text, Tpk, gws, gwn, aw,
                                     WsPk, WnPk, AwPk, edst, batch, cnt, gcnt, flags);
  k_scan<<<1, 1024, 0, stream>>>(cnt, rowstart);
  k_scatter<<<96, 256, 0, stream>>>(esrc, edst, flags, rowstart, cursor, csr);

  // ---- pipelined layer schedule (all node tensors packed) ----
  k_msgp<<<192, 256, 0, stream>>>(Pk0, cnt, rowstart, csr, Mpk);
  k_gemm<<<576, 256, 49152, stream>>>(Pk0, Mpk, WsPk, WnPk, gb, 0, flags, PkN1);
  k_postg<<<256, 256, 24832, stream>>>(PkN1, pidx, flags, gcnt, XpPkA, nullptr);
  k_scmsg<<<704, 256, 49152, stream>>>(XpPkA, Tpk, S, 192, PkN1, cnt, rowstart, csr, Mpk);
  k_stgemm<<<4928, 256, 49152, stream>>>(S, gcnt, rmax, rsum, cmaxv, csumv,
                                         576, PkN1, Mpk, WsPk + DD, WnPk + DD, gb, D, flags, PkN2);
  k_crpostg<<<4608, 256, 24832, stream>>>(S, rmax, rsum, cmaxv, csumv, gcnt, wv, t2gcol,
                                          256, PkN2, pidx, flags, XpPkB, nullptr);
  k_plscmsg<<<1024, 256, 49152, stream>>>(wv, t2gcol, Tpk, XpPkA, gcnt, pooled,
                                          512, XpPkB, S, 192, PkN2, cnt, rowstart, csr, Mpk,
                                          0, nullptr, nullptr, nullptr);
  k_stgemm<<<4928, 256, 49152, stream>>>(S, gcnt, rmax, rsum, cmaxv, csumv,
                                         576, PkN2, Mpk, WsPk + 2 * DD, WnPk + 2 * DD,
                                         gb, 2 * D, flags, PkN3);
  k_crpostg<<<4608, 256, 24832, stream>>>(S, rmax, rsum, cmaxv, csumv, gcnt, wv, t2gcol,
                                          256, PkN3, pidx, flags, XpPkA, xgacc);
  k_plscmsg<<<832, 256, 49152, stream>>>(wv, t2gcol, Tpk, XpPkB, gcnt, pooled,
                                         512, XpPkA, S, 0, nullptr, nullptr, nullptr,
                                         nullptr, nullptr, 0, nullptr, nullptr, nullptr);
  k_stgemm<<<4352, 256, 2048, stream>>>(S, gcnt, rmax, rsum, cmaxv, csumv,
                                        0, nullptr, nullptr, nullptr, nullptr,
                                        nullptr, 0, flags, nullptr);
  k_crpostg<<<4352, 256, 2048, stream>>>(S, rmax, rsum, cmaxv, csumv, gcnt, wv, t2gcol,
                                         0, nullptr, pidx, flags, nullptr, nullptr);
  k_plscmsg<<<332, 256, 4096, stream>>>(wv, t2gcol, Tpk, XpPkA, gcnt, pooled,
                                        0, nullptr, nullptr, 0, nullptr, nullptr, nullptr,
                                        nullptr, nullptr, 12, xgacc, AwPk, gpre);
  k_final<<<32, 256, 0, stream>>>(Tpk, gpre, pooled, ab, dmask, gmask, remb, flags, d_out);
}

// Round 6
// 462.986 us; speedup vs baseline: 1.0681x; 1.0681x over previous
//
#include <hip/hip_runtime.h>

#define D 768
#define B 32
#define L 512
#define M 128
#define NNODES 3072
#define NEDGES 24576

using bf16x8 = __attribute__((ext_vector_type(8))) short;
using f32x4  = __attribute__((ext_vector_type(4))) float;

__device__ __forceinline__ float bf2f(unsigned short u) {
  union { unsigned int i; float f; } v; v.i = ((unsigned int)u) << 16; return v.f;
}
__device__ __forceinline__ unsigned short f2bf(float f) {
  union { float f; unsigned int i; } v; v.f = f;
  unsigned int x = v.i;
  return (unsigned short)((x + 0x7FFFu + ((x >> 16) & 1u)) >> 16);
}
__device__ __forceinline__ float ldf(const void* p, size_t i, int f32) {
  return f32 ? ((const float*)p)[i] : bf2f(((const unsigned short*)p)[i]);
}
__device__ __forceinline__ int ldi(const void* p, size_t i, int w64) {
  return w64 ? (int)((const long long*)p)[i] : ((const int*)p)[i];
}
__device__ __forceinline__ f32x4 mfma16(bf16x8 a, bf16x8 b, f32x4 c) {
  return __builtin_amdgcn_mfma_f32_16x16x32_bf16(a, b, c, 0, 0, 0);
}
__device__ __forceinline__ void gl_lds(const unsigned short* gsrc, unsigned short* lbase,
                                       int lane) {
  __builtin_amdgcn_global_load_lds(
      (const __attribute__((address_space(1))) unsigned int*)(gsrc + lane * 8),
      (__attribute__((address_space(3))) unsigned int*)lbase, 16, 0, 0);
}

// Packed fragment layout for row-major [R x 768] bf16:
//   (row,k) -> panel p=row/16, kk=k/32, lane=((k%32)/8)*16+row%16, e=k%8
__device__ __forceinline__ float pk_read(const unsigned short* P, int p, int l, int d) {
  return bf2f(P[(((size_t)(p * 24 + (d >> 5))) << 9) + ((((d & 31) >> 3) << 4) + l) * 8 + (d & 7)]);
}

__device__ __forceinline__ void fma8(float* acc, float w, uint4 v) {
  unsigned xs[4] = {v.x, v.y, v.z, v.w};
#pragma unroll
  for (int j = 0; j < 4; ++j) {
    acc[2 * j]     += w * bf2f((unsigned short)(xs[j] & 0xFFFFu));
    acc[2 * j + 1] += w * bf2f((unsigned short)(xs[j] >> 16));
  }
}

__device__ __forceinline__ void acc12(float* a, const uint2* u) {
#pragma unroll
  for (int j = 0; j < 3; ++j) {
    a[j * 4 + 0] += bf2f((unsigned short)(u[j].x & 0xFFFFu));
    a[j * 4 + 1] += bf2f((unsigned short)(u[j].x >> 16));
    a[j * 4 + 2] += bf2f((unsigned short)(u[j].y & 0xFFFFu));
    a[j * 4 + 3] += bf2f((unsigned short)(u[j].y >> 16));
  }
}

// ================= device role bodies =================

// LDS-free pack: packed uint4 (p,kk,lane) == source row p*16+(lane&15),
// cols kk*32+(lane>>4)*8 .. +8 (8 consecutive source elements).
__device__ void d_pack_in(const void* src, unsigned short* rows, unsigned short* dst,
                          int p, int tid, int f) {
  unsigned short* pb = dst + (size_t)p * 12288;
#pragma unroll
  for (int j = 0; j < 6; ++j) {
    int odx = j * 256 + tid;
    int kk = odx >> 6, lanep = odx & 63;
    int q = lanep >> 4, r16 = lanep & 15;
    int row = p * 16 + r16, col0 = kk * 32 + q * 8;
    size_t sbase = (size_t)row * 768 + col0;
    union { unsigned short v[8]; uint4 qv; } u;
    if (f) {
      const float* sp = (const float*)src + sbase;
      float4 v0 = *(const float4*)sp;
      float4 v1 = *(const float4*)(sp + 4);
      u.v[0] = f2bf(v0.x); u.v[1] = f2bf(v0.y); u.v[2] = f2bf(v0.z); u.v[3] = f2bf(v0.w);
      u.v[4] = f2bf(v1.x); u.v[5] = f2bf(v1.y); u.v[6] = f2bf(v1.z); u.v[7] = f2bf(v1.w);
    } else {
      u.qv = *(const uint4*)((const unsigned short*)src + sbase);
    }
    if (rows) *(uint4*)&rows[sbase] = u.qv;
    *(uint4*)&pb[(size_t)odx * 8] = u.qv;
  }
}

__device__ void d_pack(const unsigned short* src, unsigned short* dst,
                       int p, int tid) {
  unsigned short* pb = dst + (size_t)p * 12288;
#pragma unroll
  for (int j = 0; j < 6; ++j) {
    int odx = j * 256 + tid;
    int kk = odx >> 6, lanep = odx & 63;
    int q = lanep >> 4, r16 = lanep & 15;
    size_t sbase = (size_t)(p * 16 + r16) * 768 + kk * 32 + q * 8;
    uint4 qv = *(const uint4*)(src + sbase);
    *(uint4*)&pb[(size_t)odx * 8] = qv;
  }
}

// LDS-free wpack: packed (pG,kk,lane,e) = W[kk*32+(lane>>4)*8+e][pG*16+(lane&15)].
__device__ void d_wpack(const void* Ws, const void* Wn, const void* Aw, int f,
                        unsigned short* WsPk, unsigned short* WnPk, unsigned short* AwPk,
                        int r0, int tid) {
  int z = r0 / 288, rem = r0 % 288;
  int nblk = rem % 12, kk = rem / 12;
  const void* src; unsigned short* dst; size_t zoff;
  if (z < 3)      { src = Ws; zoff = (size_t)z * D * D;       dst = WsPk + zoff; }
  else if (z < 6) { src = Wn; zoff = (size_t)(z - 3) * D * D; dst = WnPk + zoff; }
  else            { src = Aw; zoff = 0;                       dst = AwPk; }
  int pl = tid >> 6, lane = tid & 63;
  int pG = nblk * 4 + pl;
  int k0 = kk * 32 + ((lane >> 4) << 3);
  int n  = nblk * 64 + pl * 16 + (lane & 15);
  union { unsigned short v[8]; uint4 q; } u;
  if (f) {
    const float* sp = (const float*)src + zoff + (size_t)k0 * D + n;
#pragma unroll
    for (int e = 0; e < 8; ++e) u.v[e] = f2bf(sp[(size_t)e * D]);
  } else {
    const unsigned short* sp = (const unsigned short*)src + zoff + (size_t)k0 * D + n;
#pragma unroll
    for (int e = 0; e < 8; ++e) u.v[e] = sp[(size_t)e * D];
  }
  *(uint4*)&dst[(((size_t)(pG * 24 + kk)) << 9) + lane * 8] = u.q;
}

// count: edge atomics stay; gcnt uses sorted-run ballot (batch is sorted).
__device__ void d_count(const void* edst, const void* batch, int w,
                        int* cnt, int* gcnt, int i) {
  if (i < NEDGES) atomicAdd(&cnt[ldi(edst, i, w)], 1);
  if (i < NNODES) {
    int b = ldi(batch, i, w);
    int lane = i & 63;
    int prev = __shfl_up(b, 1);
    bool first = (lane == 0) || (prev != b);
    unsigned long long bm = __ballot(first ? 1 : 0);
    if (first) {
      unsigned long long higher = (lane < 63) ? (bm >> (lane + 1)) : 0ULL;
      int next = higher ? (lane + __ffsll((long long)higher)) : 64;
      atomicAdd(&gcnt[b], next - lane);
    }
  }
}

// msg: reads ROW-MAJOR x (coalesced full rows), writes packed Mpk. 2-row interleave.
__device__ void d_msg(const unsigned short* x, const int* cnt, const int* rowstart,
                      const int* csr, unsigned short* Mpk, int p, int tid) {
  int w = tid >> 6, lane = tid & 63;
  unsigned short* pb = Mpk + (size_t)p * 12288;
#pragma unroll
  for (int i = 0; i < 4; i += 2) {
    int rA = w * 4 + i, rB = rA + 1;
    int nA = p * 16 + rA, nB = p * 16 + rB;
    int degA = cnt[nA], baseA = rowstart[nA];
    int degB = cnt[nB], baseB = rowstart[nB];
    float aA[12], aB[12];
#pragma unroll
    for (int j = 0; j < 12; ++j) { aA[j] = 0.f; aB[j] = 0.f; }
    int dmax = degA > degB ? degA : degB;
    for (int e = 0; e < dmax; ++e) {
      uint2 uA[3], uB[3];
      if (e < degA) {
        const uint2* xr = (const uint2*)(x + (size_t)csr[baseA + e] * D);
        uA[0] = xr[lane]; uA[1] = xr[lane + 64]; uA[2] = xr[lane + 128];
      }
      if (e < degB) {
        const uint2* xr = (const uint2*)(x + (size_t)csr[baseB + e] * D);
        uB[0] = xr[lane]; uB[1] = xr[lane + 64]; uB[2] = xr[lane + 128];
      }
      if (e < degA) acc12(aA, uA);
      if (e < degB) acc12(aB, uB);
    }
    float invA = 1.0f / (float)(degA > 1 ? degA : 1);
    float invB = 1.0f / (float)(degB > 1 ? degB : 1);
#pragma unroll
    for (int j = 0; j < 3; ++j) {
      int d0 = (lane + j * 64) * 4;
      int kk = d0 >> 5, q = (d0 >> 3) & 3, e0 = d0 & 7;
      uint2 wA, wB;
      wA.x = (unsigned int)f2bf(aA[j * 4 + 0] * invA)
           | ((unsigned int)f2bf(aA[j * 4 + 1] * invA) << 16);
      wA.y = (unsigned int)f2bf(aA[j * 4 + 2] * invA)
           | ((unsigned int)f2bf(aA[j * 4 + 3] * invA) << 16);
      wB.x = (unsigned int)f2bf(aB[j * 4 + 0] * invB)
           | ((unsigned int)f2bf(aB[j * 4 + 1] * invB) << 16);
      wB.y = (unsigned int)f2bf(aB[j * 4 + 2] * invB)
           | ((unsigned int)f2bf(aB[j * 4 + 3] * invB) << 16);
      *(uint2*)&pb[kk * 512 + (q * 16 + rA) * 8 + e0] = wA;
      *(uint2*)&pb[kk * 512 + (q * 16 + rB) * 8 + e0] = wB;
    }
  }
}

// 32KB: 4 buffers x 4096 ushorts (8KB), 1-kk rounds, depth-3 prefetch,
// per-wave counted vmcnt(4) (2 loads/wave/round x 2 rounds in flight).
// 32KB -> 5 blocks/CU for every block in the fused launches.
__device__ void d_gemm(const unsigned short* Xpk, const unsigned short* Mpk,
                       const unsigned short* WsPk, const unsigned short* WnPk,
                       const void* bias, size_t bias_off, int f,
                       unsigned short* Y, int bx, int by, int tid, char* smem) {
  unsigned short* lds = (unsigned short*)smem;   // 4 * 4096 ushorts = 32KB
  int wave = tid >> 6, lane = tid & 63;
  int q = lane >> 4, t = lane & 15;
  int wm = wave >> 1, wn = wave & 1;
  int pa = bx * 4, pb = by * 4;
  f32x4 acc[2][2];
#pragma unroll
  for (int mi = 0; mi < 2; ++mi)
#pragma unroll
    for (int ni = 0; ni < 2; ++ni)
      acc[mi][ni] = (f32x4){0.f, 0.f, 0.f, 0.f};
  int c0 = wave * 2;
  int pan0 = (wave < 2) ? (pa + c0) : (pb + c0 - 4);
  auto issue = [&](int s) {
    int h = (s >= 24) ? 1 : 0;
    const unsigned short* P = (wave < 2) ? (h ? Mpk : Xpk) : (h ? WnPk : WsPk);
    int kk = s - h * 24;
    unsigned short* dbuf = &lds[(s & 3) * 4096 + c0 * 512];
    gl_lds(P + (((size_t)(pan0 * 24 + kk)) << 9), dbuf, lane);
    gl_lds(P + (((size_t)((pan0 + 1) * 24 + kk)) << 9), dbuf + 512, lane);
  };
  issue(0); issue(1); issue(2);
  for (int r = 0; r < 48; ++r) {
    if (r < 46)       asm volatile("s_waitcnt vmcnt(4)" ::: "memory");
    else if (r == 46) asm volatile("s_waitcnt vmcnt(2)" ::: "memory");
    else              asm volatile("s_waitcnt vmcnt(0)" ::: "memory");
    __builtin_amdgcn_s_barrier();
    asm volatile("" ::: "memory");
    if (r + 3 < 48) issue(r + 3);
    const unsigned short* bs = &lds[(r & 3) * 4096];
    bf16x8 a0 = *(const bf16x8*)&bs[(wm * 2 + 0) * 512 + lane * 8];
    bf16x8 a1 = *(const bf16x8*)&bs[(wm * 2 + 1) * 512 + lane * 8];
    bf16x8 b0 = *(const bf16x8*)&bs[(4 + wn * 2 + 0) * 512 + lane * 8];
    bf16x8 b1 = *(const bf16x8*)&bs[(4 + wn * 2 + 1) * 512 + lane * 8];
    acc[0][0] = mfma16(a0, b0, acc[0][0]);
    acc[0][1] = mfma16(a0, b1, acc[0][1]);
    acc[1][0] = mfma16(a1, b0, acc[1][0]);
    acc[1][1] = mfma16(a1, b1, acc[1][1]);
    asm volatile("" ::: "memory");
  }
#pragma unroll
  for (int ni = 0; ni < 2; ++ni) {
    int col = by * 64 + wn * 32 + ni * 16 + t;
    float bv = ldf(bias, bias_off + col, f);
#pragma unroll
    for (int mi = 0; mi < 2; ++mi) {
#pragma unroll
      for (int r = 0; r < 4; ++r) {
        int row = bx * 64 + wm * 32 + mi * 16 + q * 4 + r;
        float v = acc[mi][ni][r] + bv;
        Y[(size_t)row * D + col] = f2bf(v > 0.f ? v : 0.f);
      }
    }
  }
}

__device__ void d_xp(const unsigned short* Xn, const void* pidx, int w64,
                     const int* gcnt, unsigned short* xp, unsigned short* XpPk,
                     float* xgacc, int p, int tid, char* smem) {
  unsigned short* rows = (unsigned short*)smem;   // 16*776
  int r = tid >> 4, c16 = tid & 15;
  int bm = p * 16 + r;
  int b = bm >> 7, m = bm & 127;
  int nb = gcnt[b];
  uint4* dl = (uint4*)&rows[r * 776];
  uint4 v[6];
  if (m < nb) {
    const uint4* srcr = (const uint4*)(Xn + (size_t)ldi(pidx, bm, w64) * D);
#pragma unroll
    for (int j = 0; j < 6; ++j) v[j] = srcr[c16 + j * 16];
  } else {
    uint4 z = {0u, 0u, 0u, 0u};
#pragma unroll
    for (int j = 0; j < 6; ++j) v[j] = z;
  }
#pragma unroll
  for (int j = 0; j < 6; ++j) dl[c16 + j * 16] = v[j];
  __syncthreads();
#pragma unroll
  for (int j = 0; j < 6; ++j) {
    int idx = j * 256 + tid;
    int rr = idx / 96, cc = idx % 96;
    uint4 vv = *(const uint4*)&rows[rr * 776 + cc * 8];
    *(uint4*)&xp[(size_t)(p * 16 + rr) * D + cc * 8] = vv;
  }
  unsigned short* pb = XpPk + (size_t)p * 12288;
#pragma unroll
  for (int j = 0; j < 6; ++j) {
    int odx = j * 256 + tid;
    int kk = odx >> 6, lanep = odx & 63;
    int rr = lanep & 15, cg = lanep >> 4;
    int cc = kk * 4 + cg;
    uint4 vv = *(const uint4*)&rows[rr * 776 + cc * 8];
    *(uint4*)&pb[odx * 8] = vv;
  }
  if (xgacc) {
    int bb = p >> 3;
#pragma unroll
    for (int j = 0; j < 3; ++j) {
      int d = j * 256 + tid;
      float s = 0.f;
#pragma unroll
      for (int rr = 0; rr < 16; ++rr) s += bf2f(rows[rr * 776 + d]);
      atomicAdd(&xgacc[(size_t)bb * D + d], s);
    }
  }
}

// 32KB: 4 buffers, 24 1-kk rounds, depth-3, vmcnt(4).
__device__ void d_scores(const unsigned short* XpPk, const unsigned short* Tpk,
                         float* S, int bx, int by, int bz, int tid, char* smem) {
  unsigned short* lds = (unsigned short*)smem;   // 4 * 4096 ushorts = 32KB
  int wave = tid >> 6, lane = tid & 63;
  int q = lane >> 4, t = lane & 15;
  int wm = wave >> 1, wn = wave & 1;
  int pa = bz * 8 + bx * 4;
  int pb = bz * 32 + by * 4;
  f32x4 acc[2][2];
#pragma unroll
  for (int mi = 0; mi < 2; ++mi)
#pragma unroll
    for (int ni = 0; ni < 2; ++ni)
      acc[mi][ni] = (f32x4){0.f, 0.f, 0.f, 0.f};
  int c0 = wave * 2;
  const unsigned short* P = (wave < 2) ? XpPk : Tpk;
  int pan0 = (wave < 2) ? (pa + c0) : (pb + c0 - 4);
  auto issue = [&](int kk) {
    unsigned short* dbuf = &lds[(kk & 3) * 4096 + c0 * 512];
    gl_lds(P + (((size_t)(pan0 * 24 + kk)) << 9), dbuf, lane);
    gl_lds(P + (((size_t)((pan0 + 1) * 24 + kk)) << 9), dbuf + 512, lane);
  };
  issue(0); issue(1); issue(2);
  for (int r = 0; r < 24; ++r) {
    if (r < 22)       asm volatile("s_waitcnt vmcnt(4)" ::: "memory");
    else if (r == 22) asm volatile("s_waitcnt vmcnt(2)" ::: "memory");
    else              asm volatile("s_waitcnt vmcnt(0)" ::: "memory");
    __builtin_amdgcn_s_barrier();
    asm volatile("" ::: "memory");
    if (r + 3 < 24) issue(r + 3);
    const unsigned short* bs = &lds[(r & 3) * 4096];
    bf16x8 a0 = *(const bf16x8*)&bs[(wm * 2 + 0) * 512 + lane * 8];
    bf16x8 a1 = *(const bf16x8*)&bs[(wm * 2 + 1) * 512 + lane * 8];
    bf16x8 b0 = *(const bf16x8*)&bs[(4 + wn * 2 + 0) * 512 + lane * 8];
    bf16x8 b1 = *(const bf16x8*)&bs[(4 + wn * 2 + 1) * 512 + lane * 8];
    acc[0][0] = mfma16(a0, b0, acc[0][0]);
    acc[0][1] = mfma16(a0, b1, acc[0][1]);
    acc[1][0] = mfma16(a1, b0, acc[1][0]);
    acc[1][1] = mfma16(a1, b1, acc[1][1]);
    asm volatile("" ::: "memory");
  }
  float* Sb = S + (size_t)bz * M * L;
#pragma unroll
  for (int ni = 0; ni < 2; ++ni) {
    int col = by * 64 + wn * 32 + ni * 16 + t;
#pragma unroll
    for (int mi = 0; mi < 2; ++mi) {
#pragma unroll
      for (int r = 0; r < 4; ++r) {
        int row = bx * 64 + wm * 32 + mi * 16 + q * 4 + r;
        Sb[(size_t)row * L + col] = acc[mi][ni][r];
      }
    }
  }
}

__device__ void d_stats(const float* S, const int* gcnt, float* rmax, float* rsum,
                        float* cmaxv, float* csumv, int bid, int tid, char* smem) {
  if (bid < B * M) {
    float* red = (float*)smem;
    int lane = tid & 63, wv = tid >> 6;
    const float* r = S + (size_t)bid * L;
    float s0 = r[tid], s1 = r[tid + 256];
    float m = fmaxf(s0, s1);
#pragma unroll
    for (int o = 32; o > 0; o >>= 1) m = fmaxf(m, __shfl_down(m, o));
    if (lane == 0) red[wv] = m;
    __syncthreads();
    float bm = fmaxf(fmaxf(red[0], red[1]), fmaxf(red[2], red[3]));
    __syncthreads();
    float e = __expf(s0 - bm) + __expf(s1 - bm);
#pragma unroll
    for (int o = 32; o > 0; o >>= 1) e += __shfl_down(e, o);
    if (lane == 0) red[wv] = e;
    __syncthreads();
    if (tid == 0) { rmax[bid] = bm; rsum[bid] = red[0] + red[1] + red[2] + red[3]; }
  } else {
    float (*pm)[64] = (float(*)[64])smem;
    float (*ps)[64] = (float(*)[64])(smem + 1024);
    int cid = bid - B * M;
    int b = cid >> 3, ly = cid & 7;
    int w = tid >> 6, lane = tid & 63;
    int l = ly * 64 + lane;
    int nb = gcnt[b];
    const float* Sb = S + (size_t)b * M * L;
    int m0 = w * 32, m1 = min(m0 + 32, nb);
    float cm = -1e30f, cs = 0.f;
    for (int m = m0; m < m1; ++m) {
      float s = Sb[(size_t)m * L + l];
      if (s > cm) { cs = cs * __expf(cm - s) + 1.f; cm = s; }
      else cs += __expf(s - cm);
    }
    pm[w][lane] = cm; ps[w][lane] = cs;
    __syncthreads();
    if (w == 0) {
      float CM = -1e30f;
#pragma unroll
      for (int j = 0; j < 4; ++j) CM = fmaxf(CM, pm[j][lane]);
      float CS = 0.f;
#pragma unroll
      for (int j = 0; j < 4; ++j) CS += ps[j][lane] * __expf(pm[j][lane] - CM);
      cmaxv[b * L + l] = CM; csumv[b * L + l] = CS;
    }
  }
}

__device__ void d_cross(const float* S, const float* rmax, const float* rsum,
                        const float* cmaxv, const float* csumv, const int* gcnt,
                        float* wv, float* t2gcol, int bid, int tid, char* smem) {
  if (bid < 256) {
    float* rm = (float*)smem;               // 128
    float* ri = (float*)(smem + 512);       // 128
    float (*pw)[64] = (float(*)[64])(smem + 1024);
    int b = bid >> 3, ly = bid & 7;
    int w = tid >> 6, lane = tid & 63;
    if (tid < M) { rm[tid] = rmax[b * M + tid]; ri[tid] = 1.f / rsum[b * M + tid]; }
    __syncthreads();
    int l = ly * 64 + lane;
    int nb = gcnt[b];
    const float* Sb = S + (size_t)b * M * L;
    int m0 = w * 32, m1 = min(m0 + 32, nb);
    float wp = 0.f;
    for (int m = m0; m < m1; ++m)
      wp += __expf(Sb[(size_t)m * L + l] - rm[m]) * ri[m];
    pw[w][lane] = wp;
    __syncthreads();
    if (w == 0)
      wv[b * L + l] = pw[0][lane] + pw[1][lane] + pw[2][lane] + pw[3][lane];
  } else {
    float* red = (float*)smem;
    int bm = bid - 256;
    int b = bm >> 7, m = bm & 127;
    int lane = tid & 63, w = tid >> 6;
    int nb = gcnt[b];
    float acc = 0.f;
    if (m < nb) {
      const float* r = S + (size_t)bm * L;
      const float* cm = cmaxv + b * L;
      const float* cs = csumv + b * L;
      acc = __expf(r[tid] - cm[tid]) / cs[tid]
          + __expf(r[tid + 256] - cm[tid + 256]) / cs[tid + 256];
    }
#pragma unroll
    for (int o = 32; o > 0; o >>= 1) acc += __shfl_down(acc, o);
    if (lane == 0) red[w] = acc;
    __syncthreads();
    if (tid == 0) t2gcol[bm] = red[0] + red[1] + red[2] + red[3];
  }
}

// Vectorized pooled: bid = b*10 + seg. seg<8: 64 l's of wv*text; seg 8..9: 64 m's of t2gcol*xp.
__device__ void d_pooled(const float* wv, const float* t2gcol, const unsigned short* Tpk,
                         const unsigned short* xp, const int* gcnt, float* pooled,
                         int bid, int tid, char* smem) {
  float* lred = (float*)smem;
  float* wbuf = (float*)(smem + 3072);
  int b = bid / 10, seg = bid - b * 10;
  int chunk = tid % 96, half = tid / 96;
  int d = chunk * 8;
  float acc[8];
#pragma unroll
  for (int j = 0; j < 8; ++j) acc[j] = 0.f;
  if (tid < 64) {
    wbuf[tid] = (seg < 8) ? wv[b * L + seg * 64 + tid]
                          : t2gcol[b * M + (seg - 8) * 64 + tid];
  }
  __syncthreads();
  if (half < 2) {
    if (seg < 8) {
      int pbase = b * 32 + seg * 4;
      size_t cbase = ((size_t)(d >> 5)) << 9;
      int coff = ((d & 31) >> 3) << 4;
      for (int i = 0; i < 32; ++i) {
        int l = half * 32 + i;
        const unsigned short* src =
            Tpk + (((size_t)((pbase + (l >> 4)) * 24)) << 9) + cbase +
            (size_t)(coff + (l & 15)) * 8;
        fma8(acc, wbuf[l], *(const uint4*)src);
      }
    } else {
      const unsigned short* Xb = xp + (size_t)b * M * D + d;
      int m0 = (seg - 8) * 64;
      for (int i = 0; i < 32; ++i) {
        int mm = half * 32 + i;
        fma8(acc, wbuf[mm], *(const uint4*)&Xb[(size_t)(m0 + mm) * D]);
      }
    }
  }
  if (half == 1) {
#pragma unroll
    for (int j = 0; j < 8; ++j) lred[chunk * 8 + j] = acc[j];
  }
  __syncthreads();
  if (half == 0) {
    float inv = 1.f / ((float)gcnt[b] + 512.f);
#pragma unroll
    for (int j = 0; j < 8; ++j)
      atomicAdd(&pooled[(size_t)b * D + d + j], (acc[j] + lred[chunk * 8 + j]) * inv);
  }
}

__device__ void d_atom(const float* xgacc, const int* gcnt, const unsigned short* AwPk,
                       float* gpre, int bid, int tid) {
  int w = tid >> 6, lane = tid & 63;
  int q = lane >> 4, t = lane & 15;
  int nbase = bid * 64 + w * 16;
  int pb = nbase >> 4;
  int n0 = gcnt[t], n1 = gcnt[16 + t];
  float inv0 = 1.f / (float)(n0 > 1 ? n0 : 1);
  float inv1 = 1.f / (float)(n1 > 1 ? n1 : 1);
  f32x4 acc[2];
  acc[0] = (f32x4){0.f, 0.f, 0.f, 0.f};
  acc[1] = (f32x4){0.f, 0.f, 0.f, 0.f};
  for (int kk = 0; kk < 24; ++kk) {
    const float* s0 = xgacc + (size_t)t * D + kk * 32 + q * 8;
    const float* s1 = xgacc + (size_t)(16 + t) * D + kk * 32 + q * 8;
    union { unsigned short v[8]; bf16x8 f; } a0, a1;
#pragma unroll
    for (int j = 0; j < 8; ++j) { a0.v[j] = f2bf(s0[j] * inv0); a1.v[j] = f2bf(s1[j] * inv1); }
    bf16x8 bv = *(const bf16x8*)(AwPk + (((size_t)(pb * 24 + kk)) << 9) + (lane << 3));
    acc[0] = mfma16(a0.f, bv, acc[0]);
    acc[1] = mfma16(a1.f, bv, acc[1]);
  }
#pragma unroll
  for (int mi = 0; mi < 2; ++mi)
#pragma unroll
    for (int r = 0; r < 4; ++r) {
      int row = mi * 16 + q * 4 + r;
      gpre[(size_t)row * D + nbase + t] = acc[mi][r];
    }
}

// ================= global kernels =================

__global__ void k_init(int* cnt, int* cursor, int* gcnt, float* pooled, float* xgacc,
                       const unsigned short* __restrict__ t,
                       const unsigned int* __restrict__ e, int* __restrict__ flags) {
  int i = blockIdx.x * 256 + threadIdx.x;
  if (i < NNODES) { cnt[i] = 0; cursor[i] = 0; }
  if (i < B) gcnt[i] = 0;
  if (i < B * D) { pooled[i] = 0.f; xgacc[i] = 0.f; }
  if (blockIdx.x == 0) {
    __shared__ int r0[256];
    __shared__ unsigned r1[256];
    int tid = threadIdx.x;
    int bad = 0;
    for (int j = tid; j < 8192; j += 256) {
      unsigned short u = t[2 * j];
      unsigned ex = (u >> 7) & 0xFF;
      if (ex >= 0xC0) bad = 1;
    }
    unsigned o = 0;
    for (int j = tid; j < NEDGES / 2; j += 256) o |= e[2 * j + 1];
    r0[tid] = bad; r1[tid] = o;
    __syncthreads();
    for (int s = 128; s > 0; s >>= 1) {
      if (tid < s) { r0[tid] |= r0[tid + s]; r1[tid] |= r1[tid + s]; }
      __syncthreads();
    }
    if (tid == 0) { flags[0] = r0[0]; flags[1] = (r1[0] == 0) ? 1 : 0; }
  }
}

// pack_in (0..1215) + wpack (1216..3231) + count (3232..3327); no LDS.
__global__ __launch_bounds__(256) void k_setup2(
    const void* x_in, unsigned short* x0, unsigned short* PkA,
    const void* text, unsigned short* Tpk,
    const void* Ws, const void* Wn, const void* Aw,
    unsigned short* WsPk, unsigned short* WnPk, unsigned short* AwPk,
    const void* edst, const void* batch, int* cnt, int* gcnt,
    const int* __restrict__ flags) {
  int bid = blockIdx.x, tid = threadIdx.x;
  if (bid < 1216) {
    int f = flags[0];
    if (bid < NNODES / 16) d_pack_in(x_in, x0, PkA, bid, tid, f);
    else d_pack_in(text, nullptr, Tpk, bid - NNODES / 16, tid, f);
  } else if (bid < 3232) {
    d_wpack(Ws, Wn, Aw, flags[0], WsPk, WnPk, AwPk, bid - 1216, tid);
  } else {
    d_count(edst, batch, flags[1], cnt, gcnt, (bid - 3232) * 256 + tid);
  }
}

__global__ void k_scan(const int* __restrict__ cnt, int* __restrict__ rowstart) {
  __shared__ int a[NNODES], b[NNODES];
  int tid = threadIdx.x;
  for (int i = tid; i < NNODES; i += 1024) a[i] = cnt[i];
  __syncthreads();
  int* s = a; int* d = b;
  for (int off = 1; off < NNODES; off <<= 1) {
    for (int i = tid; i < NNODES; i += 1024)
      d[i] = s[i] + (i >= off ? s[i - off] : 0);
    __syncthreads();
    int* t = s; s = d; d = t;
  }
  for (int i = tid; i < NNODES; i += 1024) rowstart[i + 1] = s[i];
  if (tid == 0) rowstart[0] = 0;
}

__global__ void k_scatter(const void* __restrict__ esrc, const void* __restrict__ edst,
                          const int* __restrict__ flags, const int* __restrict__ rowstart,
                          int* __restrict__ cursor, int* __restrict__ csr) {
  int w = flags[1];
  int i = blockIdx.x * 256 + threadIdx.x;
  if (i < NEDGES) {
    int dd = ldi(edst, i, w);
    int pos = atomicAdd(&cursor[dd], 1);
    csr[rowstart[dd] + pos] = ldi(esrc, i, w);
  }
}

__global__ __launch_bounds__(256) void k_msgp(
    const unsigned short* x, const int* cnt, const int* rowstart, const int* csr,
    unsigned short* Mpk) {
  d_msg(x, cnt, rowstart, csr, Mpk, blockIdx.x, threadIdx.x);
}

// XCD-bijective swizzles (grid%8==0 in both uses).
__device__ __forceinline__ void gemm_map(int g, int& bx, int& by) {
  int gs = (g % 8) * 72 + g / 8;   // 576 = 8*72; same-bx blocks land on one XCD
  bx = gs / 12; by = gs % 12;
}
__device__ __forceinline__ void sc_map(int g, int& bx, int& by, int& bz) {
  int gs = (g % 8) * 64 + g / 8;   // 512 = 8*64; same-bz blocks land on one XCD
  bx = gs & 1; by = (gs >> 1) & 7; bz = gs >> 4;
}

__global__ __launch_bounds__(256) void k_gemm(
    const unsigned short* Apk, const unsigned short* Mpk,
    const unsigned short* WsPk, const unsigned short* WnPk,
    const void* bias, unsigned long bias_off, const int* flags, unsigned short* Y) {
  extern __shared__ char smem[];
  int bx, by; gemm_map(blockIdx.x, bx, by);
  d_gemm(Apk, Mpk, WsPk, WnPk, bias, bias_off, flags[0], Y, bx, by,
         threadIdx.x, smem);
}

// pack (0..packN-1) + xp_pack (packN..packN+255)
__global__ __launch_bounds__(256) void k_postg(
    const unsigned short* Y, unsigned short* Npk, int packN,
    const void* pidx, const int* flags, const int* gcnt,
    unsigned short* xp, unsigned short* XpPk, float* xgacc) {
  extern __shared__ char smem[];
  int bid = blockIdx.x, tid = threadIdx.x;
  if (bid < packN) d_pack(Y, Npk, bid, tid);
  else d_xp(Y, pidx, flags[1], gcnt, xp, XpPk, xgacc, bid - packN, tid, smem);
}

// scores (0..511) + msg(next) (512..512+msgN-1)
__global__ __launch_bounds__(256) void k_scmsg(
    const unsigned short* XpPk, const unsigned short* Tpk, float* S,
    int msgN, const unsigned short* x, const int* cnt, const int* rowstart,
    const int* csr, unsigned short* Mpk) {
  extern __shared__ char smem[];
  int bid = blockIdx.x, tid = threadIdx.x;
  if (bid < 512) {
    int bx, by, bz; sc_map(bid, bx, by, bz);
    d_scores(XpPk, Tpk, S, bx, by, bz, tid, smem);
  } else d_msg(x, cnt, rowstart, csr, Mpk, bid - 512, tid);
}

// stats (0..4351) + gemm(next) (4352..4352+gemmN-1)
__global__ __launch_bounds__(256) void k_stgemm(
    const float* S, const int* gcnt, float* rmax, float* rsum, float* cmaxv, float* csumv,
    int gemmN, const unsigned short* Apk, const unsigned short* Mpk,
    const unsigned short* WsPk, const unsigned short* WnPk,
    const void* bias, unsigned long bias_off, const int* flags, unsigned short* Y) {
  extern __shared__ char smem[];
  int bid = blockIdx.x, tid = threadIdx.x;
  if (bid < 4352) d_stats(S, gcnt, rmax, rsum, cmaxv, csumv, bid, tid, smem);
  else {
    int bx, by; gemm_map(bid - 4352, bx, by);
    d_gemm(Apk, Mpk, WsPk, WnPk, bias, bias_off, flags[0], Y, bx, by, tid, smem);
  }
}

// cross (0..4351) + pack(next) + xp_pack(next)
__global__ __launch_bounds__(256) void k_crpostg(
    const float* S, const float* rmax, const float* rsum, const float* cmaxv,
    const float* csumv, const int* gcnt, float* wv, float* t2gcol,
    int packN, int xpN, const unsigned short* Y, unsigned short* Npk,
    const void* pidx, const int* flags, unsigned short* xp, unsigned short* XpPk,
    float* xgacc) {
  extern __shared__ char smem[];
  int bid = blockIdx.x, tid = threadIdx.x;
  if (bid < 4352) d_cross(S, rmax, rsum, cmaxv, csumv, gcnt, wv, t2gcol, bid, tid, smem);
  else {
    int r = bid - 4352;
    if (r < packN) d_pack(Y, Npk, r, tid);
    else d_xp(Y, pidx, flags[1], gcnt, xp, XpPk, xgacc, r - packN, tid, smem);
  }
}

// pooled (0..319) + scores(next) (320..320+scN-1) + msg (then msgN) + atom (then atomN)
__global__ __launch_bounds__(256) void k_plscmsg(
    const float* wv, const float* t2gcol, const unsigned short* Tpk,
    const unsigned short* xpL, const int* gcnt, float* pooled,
    int scN, const unsigned short* XpPk, float* S,
    int msgN, const unsigned short* x, const int* cnt, const int* rowstart,
    const int* csr, unsigned short* Mpk,
    int atomN, const float* xgacc, const unsigned short* AwPk, float* gpre) {
  extern __shared__ char smem[];
  int bid = blockIdx.x, tid = threadIdx.x;
  if (bid < 320) { d_pooled(wv, t2gcol, Tpk, xpL, gcnt, pooled, bid, tid, smem); return; }
  int r = bid - 320;
  if (r < scN) {
    int bx, by, bz; sc_map(r, bx, by, bz);
    d_scores(XpPk, Tpk, S, bx, by, bz, tid, smem); return;
  }
  r -= scN;
  if (r < msgN) { d_msg(x, cnt, rowstart, csr, Mpk, r, tid); return; }
  d_atom(xgacc, gcnt, AwPk, gpre, r - msgN, tid);
}

__global__ __launch_bounds__(256) void k_final(
    const unsigned short* __restrict__ Tpk, const float* __restrict__ gpre,
    const float* __restrict__ pooled, const void* __restrict__ ab,
    const void* __restrict__ dmask, const void* __restrict__ gmask,
    const void* __restrict__ remb, const int* __restrict__ flags,
    void* __restrict__ out) {
  int f = flags[0];
  int b = blockIdx.x, tid = threadIdx.x;
  float dm = ldf(dmask, b, f);
  float gm = ldf(gmask, b, f);
  float dg = dm * gm;
  size_t base = (size_t)b * 2304;
#pragma unroll
  for (int j = 0; j < 3; ++j) {
    int d = tid + j * 256;
    float z = ldf(remb, d, f);
    float tv = pk_read(Tpk, b * 32, 0, d);
    float o0 = tv * dm + (1.f - dm) * z;
    float gv = tanhf(gpre[(size_t)b * D + d] + ldf(ab, d, f));
    float o1 = gv * gm + (1.f - gm) * z;
    float p = pooled[(size_t)b * D + d] * (1.f / 3.f);
    float o2 = p * dg + (1.f - dg) * z;
    if (f) {
      float* of = (float*)out;
      of[base + d] = o0; of[base + 768 + d] = o1; of[base + 1536 + d] = o2;
    } else {
      unsigned short* ob = (unsigned short*)out;
      ob[base + d] = f2bf(o0); ob[base + 768 + d] = f2bf(o1); ob[base + 1536 + d] = f2bf(o2);
    }
  }
}

extern "C" void kernel_launch(void* const* d_in, const int* in_sizes, int n_in,
                              void* d_out, int out_size, void* d_ws, size_t ws_size,
                              hipStream_t stream) {
  const void* x_in  = d_in[0];
  const void* text  = d_in[1];
  const void* dmask = d_in[2];
  const void* gmask = d_in[3];
  const void* gws   = d_in[4];
  const void* gwn   = d_in[5];
  const void* gb    = d_in[6];
  const void* aw    = d_in[7];
  const void* ab    = d_in[8];
  const void* remb  = d_in[9];
  const void* batch = d_in[10];
  const void* pidx  = d_in[11];
  const void* esrc  = d_in[13];
  const void* edst  = d_in[14];

  char* wsp = (char*)d_ws;
  size_t off = 0;
  auto carve = [&](size_t bytes) -> void* {
    void* p = wsp + off;
    off += (bytes + 255) & ~(size_t)255;
    return p;
  };
  int* flags = (int*)carve(2 * 4);
  unsigned short* x0    = (unsigned short*)carve((size_t)NNODES * D * 2);
  unsigned short* xA    = (unsigned short*)carve((size_t)NNODES * D * 2);
  unsigned short* xB    = (unsigned short*)carve((size_t)NNODES * D * 2);
  unsigned short* PkA   = (unsigned short*)carve((size_t)NNODES * D * 2);
  unsigned short* PkB   = (unsigned short*)carve((size_t)NNODES * D * 2);
  unsigned short* Mpk   = (unsigned short*)carve((size_t)NNODES * D * 2);
  unsigned short* Tpk   = (unsigned short*)carve((size_t)B * L * D * 2);
  unsigned short* WsPk  = (unsigned short*)carve((size_t)3 * D * D * 2);
  unsigned short* WnPk  = (unsigned short*)carve((size_t)3 * D * D * 2);
  unsigned short* AwPk  = (unsigned short*)carve((size_t)D * D * 2);
  unsigned short* xpA   = (unsigned short*)carve((size_t)B * M * D * 2);
  unsigned short* xpB   = (unsigned short*)carve((size_t)B * M * D * 2);
  unsigned short* XpPkA = (unsigned short*)carve((size_t)B * M * D * 2);
  unsigned short* XpPkB = (unsigned short*)carve((size_t)B * M * D * 2);
  float* xgacc   = (float*)carve((size_t)B * D * 4);
  float* gpre    = (float*)carve((size_t)B * D * 4);
  float* S       = (float*)carve((size_t)B * M * L * 4);
  float* rmax    = (float*)carve((size_t)B * M * 4);
  float* rsum    = (float*)carve((size_t)B * M * 4);
  float* wv      = (float*)carve((size_t)B * L * 4);
  float* cmaxv   = (float*)carve((size_t)B * L * 4);
  float* csumv   = (float*)carve((size_t)B * L * 4);
  float* t2gcol  = (float*)carve((size_t)B * M * 4);
  float* pooled  = (float*)carve((size_t)B * D * 4);
  int* cnt      = (int*)carve((size_t)NNODES * 4);
  int* rowstart = (int*)carve((size_t)(NNODES + 1) * 4);
  int* cursor   = (int*)carve((size_t)NNODES * 4);
  int* gcnt     = (int*)carve((size_t)B * 4);
  int* csr      = (int*)carve((size_t)NEDGES * 4);

  const size_t DD = (size_t)D * D;

  k_init<<<96, 256, 0, stream>>>(cnt, cursor, gcnt, pooled, xgacc,
                                 (const unsigned short*)text, (const unsigned int*)edst, flags);
  k_setup2<<<3328, 256, 0, stream>>>(x_in, x0, PkA, text, Tpk, gws, gwn, aw,
                                     WsPk, WnPk, AwPk, edst, batch, cnt, gcnt, flags);
  k_scan<<<1, 1024, 0, stream>>>(cnt, rowstart);
  k_scatter<<<96, 256, 0, stream>>>(esrc, edst, flags, rowstart, cursor, csr);

  // ---- pipelined layer schedule ----
  k_msgp<<<192, 256, 0, stream>>>(x0, cnt, rowstart, csr, Mpk);
  k_gemm<<<576, 256, 32768, stream>>>(PkA, Mpk, WsPk, WnPk, gb, 0, flags, xA);
  k_postg<<<448, 256, 24832, stream>>>(xA, PkB, 192, pidx, flags, gcnt, xpA, XpPkA, nullptr);
  k_scmsg<<<704, 256, 32768, stream>>>(XpPkA, Tpk, S, 192, xA, cnt, rowstart, csr, Mpk);
  k_stgemm<<<4928, 256, 32768, stream>>>(S, gcnt, rmax, rsum, cmaxv, csumv,
                                         576, PkB, Mpk, WsPk + DD, WnPk + DD, gb, D, flags, xB);
  k_crpostg<<<4800, 256, 24832, stream>>>(S, rmax, rsum, cmaxv, csumv, gcnt, wv, t2gcol,
                                          192, 256, xB, PkA, pidx, flags, xpB, XpPkB, nullptr);
  k_plscmsg<<<1024, 256, 32768, stream>>>(wv, t2gcol, Tpk, xpA, gcnt, pooled,
                                          512, XpPkB, S, 192, xB, cnt, rowstart, csr, Mpk,
                                          0, nullptr, nullptr, nullptr);
  k_stgemm<<<4928, 256, 32768, stream>>>(S, gcnt, rmax, rsum, cmaxv, csumv,
                                         576, PkA, Mpk, WsPk + 2 * DD, WnPk + 2 * DD,
                                         gb, 2 * D, flags, xA);
  k_crpostg<<<4608, 256, 24832, stream>>>(S, rmax, rsum, cmaxv, csumv, gcnt, wv, t2gcol,
                                          0, 256, xA, nullptr, pidx, flags, xpA, XpPkA, xgacc);
  k_plscmsg<<<832, 256, 32768, stream>>>(wv, t2gcol, Tpk, xpB, gcnt, pooled,
                                         512, XpPkA, S, 0, nullptr, nullptr, nullptr,
                                         nullptr, nullptr, 0, nullptr, nullptr, nullptr);
  k_stgemm<<<4352, 256, 2048, stream>>>(S, gcnt, rmax, rsum, cmaxv, csumv,
                                        0, nullptr, nullptr, nullptr, nullptr,
                                        nullptr, 0, flags, nullptr);
  k_crpostg<<<4352, 256, 2048, stream>>>(S, rmax, rsum, cmaxv, csumv, gcnt, wv, t2gcol,
                                         0, 0, nullptr, nullptr, pidx, flags,
                                         nullptr, nullptr, nullptr);
  k_plscmsg<<<332, 256, 4096, stream>>>(wv, t2gcol, Tpk, xpA, gcnt, pooled,
                                        0, nullptr, nullptr, 0, nullptr, nullptr, nullptr,
                                        nullptr, nullptr, 12, xgacc, AwPk, gpre);
  k_final<<<32, 256, 0, stream>>>(Tpk, gpre, pooled, ab, dmask, gmask, remb, flags, d_out);
}

// Round 7
// 421.169 us; speedup vs baseline: 1.1741x; 1.0993x over previous
//
#include <hip/hip_runtime.h>

#define D 768
#define B 32
#define L 512
#define M 128
#define NNODES 3072
#define NEDGES 24576

using bf16x8 = __attribute__((ext_vector_type(8))) short;
using f32x4  = __attribute__((ext_vector_type(4))) float;

__device__ __forceinline__ float bf2f(unsigned short u) {
  union { unsigned int i; float f; } v; v.i = ((unsigned int)u) << 16; return v.f;
}
__device__ __forceinline__ unsigned short f2bf(float f) {
  union { float f; unsigned int i; } v; v.f = f;
  unsigned int x = v.i;
  return (unsigned short)((x + 0x7FFFu + ((x >> 16) & 1u)) >> 16);
}
__device__ __forceinline__ float ldf(const void* p, size_t i, int f32) {
  return f32 ? ((const float*)p)[i] : bf2f(((const unsigned short*)p)[i]);
}
__device__ __forceinline__ int ldi(const void* p, size_t i, int w64) {
  return w64 ? (int)((const long long*)p)[i] : ((const int*)p)[i];
}
__device__ __forceinline__ f32x4 mfma16(bf16x8 a, bf16x8 b, f32x4 c) {
  return __builtin_amdgcn_mfma_f32_16x16x32_bf16(a, b, c, 0, 0, 0);
}

// Packed fragment layout for row-major [R x 768] bf16:
//   (row,k) -> panel p=row/16, kk=k/32, lane=((k%32)/8)*16+row%16, e=k%8
// A wave's MFMA fragment for (panel,kk) is the contiguous 16B at
//   base + ((panel*24+kk)<<9) + lane*8  -> direct global->register loads.
__device__ __forceinline__ float pk_read(const unsigned short* P, int p, int l, int d) {
  return bf2f(P[(((size_t)(p * 24 + (d >> 5))) << 9) + ((((d & 31) >> 3) << 4) + l) * 8 + (d & 7)]);
}

__device__ __forceinline__ void fma8(float* acc, float w, uint4 v) {
  unsigned xs[4] = {v.x, v.y, v.z, v.w};
#pragma unroll
  for (int j = 0; j < 4; ++j) {
    acc[2 * j]     += w * bf2f((unsigned short)(xs[j] & 0xFFFFu));
    acc[2 * j + 1] += w * bf2f((unsigned short)(xs[j] >> 16));
  }
}

__device__ __forceinline__ void acc12(float* a, const uint2* u) {
#pragma unroll
  for (int j = 0; j < 3; ++j) {
    a[j * 4 + 0] += bf2f((unsigned short)(u[j].x & 0xFFFFu));
    a[j * 4 + 1] += bf2f((unsigned short)(u[j].x >> 16));
    a[j * 4 + 2] += bf2f((unsigned short)(u[j].y & 0xFFFFu));
    a[j * 4 + 3] += bf2f((unsigned short)(u[j].y >> 16));
  }
}

// ================= device role bodies =================

// LDS-free pack: packed uint4 (p,kk,lane) == source row p*16+(lane&15),
// cols kk*32+(lane>>4)*8 .. +8 (8 consecutive source elements).
__device__ void d_pack_in(const void* src, unsigned short* rows, unsigned short* dst,
                          int p, int tid, int f) {
  unsigned short* pb = dst + (size_t)p * 12288;
#pragma unroll
  for (int j = 0; j < 6; ++j) {
    int odx = j * 256 + tid;
    int kk = odx >> 6, lanep = odx & 63;
    int q = lanep >> 4, r16 = lanep & 15;
    int row = p * 16 + r16, col0 = kk * 32 + q * 8;
    size_t sbase = (size_t)row * 768 + col0;
    union { unsigned short v[8]; uint4 qv; } u;
    if (f) {
      const float* sp = (const float*)src + sbase;
      float4 v0 = *(const float4*)sp;
      float4 v1 = *(const float4*)(sp + 4);
      u.v[0] = f2bf(v0.x); u.v[1] = f2bf(v0.y); u.v[2] = f2bf(v0.z); u.v[3] = f2bf(v0.w);
      u.v[4] = f2bf(v1.x); u.v[5] = f2bf(v1.y); u.v[6] = f2bf(v1.z); u.v[7] = f2bf(v1.w);
    } else {
      u.qv = *(const uint4*)((const unsigned short*)src + sbase);
    }
    if (rows) *(uint4*)&rows[sbase] = u.qv;
    *(uint4*)&pb[(size_t)odx * 8] = u.qv;
  }
}

__device__ void d_pack(const unsigned short* src, unsigned short* dst,
                       int p, int tid) {
  unsigned short* pb = dst + (size_t)p * 12288;
#pragma unroll
  for (int j = 0; j < 6; ++j) {
    int odx = j * 256 + tid;
    int kk = odx >> 6, lanep = odx & 63;
    int q = lanep >> 4, r16 = lanep & 15;
    size_t sbase = (size_t)(p * 16 + r16) * 768 + kk * 32 + q * 8;
    uint4 qv = *(const uint4*)(src + sbase);
    *(uint4*)&pb[(size_t)odx * 8] = qv;
  }
}

// LDS-free wpack: packed (pG,kk,lane,e) = W[kk*32+(lane>>4)*8+e][pG*16+(lane&15)].
__device__ void d_wpack(const void* Ws, const void* Wn, const void* Aw, int f,
                        unsigned short* WsPk, unsigned short* WnPk, unsigned short* AwPk,
                        int r0, int tid) {
  int z = r0 / 288, rem = r0 % 288;
  int nblk = rem % 12, kk = rem / 12;
  const void* src; unsigned short* dst; size_t zoff;
  if (z < 3)      { src = Ws; zoff = (size_t)z * D * D;       dst = WsPk + zoff; }
  else if (z < 6) { src = Wn; zoff = (size_t)(z - 3) * D * D; dst = WnPk + zoff; }
  else            { src = Aw; zoff = 0;                       dst = AwPk; }
  int pl = tid >> 6, lane = tid & 63;
  int pG = nblk * 4 + pl;
  int k0 = kk * 32 + ((lane >> 4) << 3);
  int n  = nblk * 64 + pl * 16 + (lane & 15);
  union { unsigned short v[8]; uint4 q; } u;
  if (f) {
    const float* sp = (const float*)src + zoff + (size_t)k0 * D + n;
#pragma unroll
    for (int e = 0; e < 8; ++e) u.v[e] = f2bf(sp[(size_t)e * D]);
  } else {
    const unsigned short* sp = (const unsigned short*)src + zoff + (size_t)k0 * D + n;
#pragma unroll
    for (int e = 0; e < 8; ++e) u.v[e] = sp[(size_t)e * D];
  }
  *(uint4*)&dst[(((size_t)(pG * 24 + kk)) << 9) + lane * 8] = u.q;
}

// count: edge atomics stay; gcnt uses sorted-run ballot (batch is sorted).
__device__ void d_count(const void* edst, const void* batch, int w,
                        int* cnt, int* gcnt, int i) {
  if (i < NEDGES) atomicAdd(&cnt[ldi(edst, i, w)], 1);
  if (i < NNODES) {
    int b = ldi(batch, i, w);
    int lane = i & 63;
    int prev = __shfl_up(b, 1);
    bool first = (lane == 0) || (prev != b);
    unsigned long long bm = __ballot(first ? 1 : 0);
    if (first) {
      unsigned long long higher = (lane < 63) ? (bm >> (lane + 1)) : 0ULL;
      int next = higher ? (lane + __ffsll((long long)higher)) : 64;
      atomicAdd(&gcnt[b], next - lane);
    }
  }
}

// msg: reads ROW-MAJOR x (coalesced full rows), writes packed Mpk. 2-row interleave.
__device__ void d_msg(const unsigned short* x, const int* cnt, const int* rowstart,
                      const int* csr, unsigned short* Mpk, int p, int tid) {
  int w = tid >> 6, lane = tid & 63;
  unsigned short* pb = Mpk + (size_t)p * 12288;
#pragma unroll
  for (int i = 0; i < 4; i += 2) {
    int rA = w * 4 + i, rB = rA + 1;
    int nA = p * 16 + rA, nB = p * 16 + rB;
    int degA = cnt[nA], baseA = rowstart[nA];
    int degB = cnt[nB], baseB = rowstart[nB];
    float aA[12], aB[12];
#pragma unroll
    for (int j = 0; j < 12; ++j) { aA[j] = 0.f; aB[j] = 0.f; }
    int dmax = degA > degB ? degA : degB;
    for (int e = 0; e < dmax; ++e) {
      uint2 uA[3], uB[3];
      if (e < degA) {
        const uint2* xr = (const uint2*)(x + (size_t)csr[baseA + e] * D);
        uA[0] = xr[lane]; uA[1] = xr[lane + 64]; uA[2] = xr[lane + 128];
      }
      if (e < degB) {
        const uint2* xr = (const uint2*)(x + (size_t)csr[baseB + e] * D);
        uB[0] = xr[lane]; uB[1] = xr[lane + 64]; uB[2] = xr[lane + 128];
      }
      if (e < degA) acc12(aA, uA);
      if (e < degB) acc12(aB, uB);
    }
    float invA = 1.0f / (float)(degA > 1 ? degA : 1);
    float invB = 1.0f / (float)(degB > 1 ? degB : 1);
#pragma unroll
    for (int j = 0; j < 3; ++j) {
      int d0 = (lane + j * 64) * 4;
      int kk = d0 >> 5, q = (d0 >> 3) & 3, e0 = d0 & 7;
      uint2 wA, wB;
      wA.x = (unsigned int)f2bf(aA[j * 4 + 0] * invA)
           | ((unsigned int)f2bf(aA[j * 4 + 1] * invA) << 16);
      wA.y = (unsigned int)f2bf(aA[j * 4 + 2] * invA)
           | ((unsigned int)f2bf(aA[j * 4 + 3] * invA) << 16);
      wB.x = (unsigned int)f2bf(aB[j * 4 + 0] * invB)
           | ((unsigned int)f2bf(aB[j * 4 + 1] * invB) << 16);
      wB.y = (unsigned int)f2bf(aB[j * 4 + 2] * invB)
           | ((unsigned int)f2bf(aB[j * 4 + 3] * invB) << 16);
      *(uint2*)&pb[kk * 512 + (q * 16 + rA) * 8 + e0] = wA;
      *(uint2*)&pb[kk * 512 + (q * 16 + rB) * 8 + e0] = wB;
    }
  }
}

// BARRIER-FREE GEMM: each wave streams its MFMA fragments directly from
// global (packed layout, lane-contiguous 16B) into registers. No LDS,
// no __syncthreads, no manual waitcnt — compiler pipelines the loads,
// resident waves provide TLP. Accumulation order identical to the LDS
// version (X@Ws kk=0..23, then M@Wn kk=0..23) -> bit-identical output.
__device__ void d_gemm(const unsigned short* Xpk, const unsigned short* Mpk,
                       const unsigned short* WsPk, const unsigned short* WnPk,
                       const void* bias, size_t bias_off, int f,
                       unsigned short* Y, int bx, int by, int tid) {
  int wave = tid >> 6, lane = tid & 63;
  int q = lane >> 4, t = lane & 15;
  int wm = wave >> 1, wn = wave & 1;
  const int PAN = 24 << 9;   // panel stride in ushorts
  f32x4 acc[2][2];
#pragma unroll
  for (int mi = 0; mi < 2; ++mi)
#pragma unroll
    for (int ni = 0; ni < 2; ++ni)
      acc[mi][ni] = (f32x4){0.f, 0.f, 0.f, 0.f};
  size_t aoff = (((size_t)((bx * 4 + wm * 2) * 24)) << 9) + lane * 8;
  size_t boff = (((size_t)((by * 4 + wn * 2) * 24)) << 9) + lane * 8;
  {
    const unsigned short* A = Xpk + aoff;
    const unsigned short* Bp = WsPk + boff;
#pragma unroll 4
    for (int kk = 0; kk < 24; ++kk) {
      bf16x8 a0 = *(const bf16x8*)(A + kk * 512);
      bf16x8 a1 = *(const bf16x8*)(A + kk * 512 + PAN);
      bf16x8 b0 = *(const bf16x8*)(Bp + kk * 512);
      bf16x8 b1 = *(const bf16x8*)(Bp + kk * 512 + PAN);
      acc[0][0] = mfma16(a0, b0, acc[0][0]);
      acc[0][1] = mfma16(a0, b1, acc[0][1]);
      acc[1][0] = mfma16(a1, b0, acc[1][0]);
      acc[1][1] = mfma16(a1, b1, acc[1][1]);
    }
  }
  {
    const unsigned short* A = Mpk + aoff;
    const unsigned short* Bp = WnPk + boff;
#pragma unroll 4
    for (int kk = 0; kk < 24; ++kk) {
      bf16x8 a0 = *(const bf16x8*)(A + kk * 512);
      bf16x8 a1 = *(const bf16x8*)(A + kk * 512 + PAN);
      bf16x8 b0 = *(const bf16x8*)(Bp + kk * 512);
      bf16x8 b1 = *(const bf16x8*)(Bp + kk * 512 + PAN);
      acc[0][0] = mfma16(a0, b0, acc[0][0]);
      acc[0][1] = mfma16(a0, b1, acc[0][1]);
      acc[1][0] = mfma16(a1, b0, acc[1][0]);
      acc[1][1] = mfma16(a1, b1, acc[1][1]);
    }
  }
#pragma unroll
  for (int ni = 0; ni < 2; ++ni) {
    int col = by * 64 + wn * 32 + ni * 16 + t;
    float bv = ldf(bias, bias_off + col, f);
#pragma unroll
    for (int mi = 0; mi < 2; ++mi) {
#pragma unroll
      for (int r = 0; r < 4; ++r) {
        int row = bx * 64 + wm * 32 + mi * 16 + q * 4 + r;
        float v = acc[mi][ni][r] + bv;
        Y[(size_t)row * D + col] = f2bf(v > 0.f ? v : 0.f);
      }
    }
  }
}

__device__ void d_xp(const unsigned short* Xn, const void* pidx, int w64,
                     const int* gcnt, unsigned short* xp, unsigned short* XpPk,
                     float* xgacc, int p, int tid, char* smem) {
  unsigned short* rows = (unsigned short*)smem;   // 16*776
  int r = tid >> 4, c16 = tid & 15;
  int bm = p * 16 + r;
  int b = bm >> 7, m = bm & 127;
  int nb = gcnt[b];
  uint4* dl = (uint4*)&rows[r * 776];
  uint4 v[6];
  if (m < nb) {
    const uint4* srcr = (const uint4*)(Xn + (size_t)ldi(pidx, bm, w64) * D);
#pragma unroll
    for (int j = 0; j < 6; ++j) v[j] = srcr[c16 + j * 16];
  } else {
    uint4 z = {0u, 0u, 0u, 0u};
#pragma unroll
    for (int j = 0; j < 6; ++j) v[j] = z;
  }
#pragma unroll
  for (int j = 0; j < 6; ++j) dl[c16 + j * 16] = v[j];
  __syncthreads();
#pragma unroll
  for (int j = 0; j < 6; ++j) {
    int idx = j * 256 + tid;
    int rr = idx / 96, cc = idx % 96;
    uint4 vv = *(const uint4*)&rows[rr * 776 + cc * 8];
    *(uint4*)&xp[(size_t)(p * 16 + rr) * D + cc * 8] = vv;
  }
  unsigned short* pb = XpPk + (size_t)p * 12288;
#pragma unroll
  for (int j = 0; j < 6; ++j) {
    int odx = j * 256 + tid;
    int kk = odx >> 6, lanep = odx & 63;
    int rr = lanep & 15, cg = lanep >> 4;
    int cc = kk * 4 + cg;
    uint4 vv = *(const uint4*)&rows[rr * 776 + cc * 8];
    *(uint4*)&pb[odx * 8] = vv;
  }
  if (xgacc) {
    int bb = p >> 3;
#pragma unroll
    for (int j = 0; j < 3; ++j) {
      int d = j * 256 + tid;
      float s = 0.f;
#pragma unroll
      for (int rr = 0; rr < 16; ++rr) s += bf2f(rows[rr * 776 + d]);
      atomicAdd(&xgacc[(size_t)bb * D + d], s);
    }
  }
}

// BARRIER-FREE scores: direct global->register fragment streams, 24 kk.
__device__ void d_scores(const unsigned short* XpPk, const unsigned short* Tpk,
                         float* S, int bx, int by, int bz, int tid) {
  int wave = tid >> 6, lane = tid & 63;
  int q = lane >> 4, t = lane & 15;
  int wm = wave >> 1, wn = wave & 1;
  const int PAN = 24 << 9;
  f32x4 acc[2][2];
#pragma unroll
  for (int mi = 0; mi < 2; ++mi)
#pragma unroll
    for (int ni = 0; ni < 2; ++ni)
      acc[mi][ni] = (f32x4){0.f, 0.f, 0.f, 0.f};
  size_t aoff = (((size_t)((bz * 8 + bx * 4 + wm * 2) * 24)) << 9) + lane * 8;
  size_t boff = (((size_t)((bz * 32 + by * 4 + wn * 2) * 24)) << 9) + lane * 8;
  const unsigned short* A = XpPk + aoff;
  const unsigned short* Bp = Tpk + boff;
#pragma unroll 4
  for (int kk = 0; kk < 24; ++kk) {
    bf16x8 a0 = *(const bf16x8*)(A + kk * 512);
    bf16x8 a1 = *(const bf16x8*)(A + kk * 512 + PAN);
    bf16x8 b0 = *(const bf16x8*)(Bp + kk * 512);
    bf16x8 b1 = *(const bf16x8*)(Bp + kk * 512 + PAN);
    acc[0][0] = mfma16(a0, b0, acc[0][0]);
    acc[0][1] = mfma16(a0, b1, acc[0][1]);
    acc[1][0] = mfma16(a1, b0, acc[1][0]);
    acc[1][1] = mfma16(a1, b1, acc[1][1]);
  }
  float* Sb = S + (size_t)bz * M * L;
#pragma unroll
  for (int ni = 0; ni < 2; ++ni) {
    int col = by * 64 + wn * 32 + ni * 16 + t;
#pragma unroll
    for (int mi = 0; mi < 2; ++mi) {
#pragma unroll
      for (int r = 0; r < 4; ++r) {
        int row = bx * 64 + wm * 32 + mi * 16 + q * 4 + r;
        Sb[(size_t)row * L + col] = acc[mi][ni][r];
      }
    }
  }
}

__device__ void d_stats(const float* S, const int* gcnt, float* rmax, float* rsum,
                        float* cmaxv, float* csumv, int bid, int tid, char* smem) {
  if (bid < B * M) {
    float* red = (float*)smem;
    int lane = tid & 63, wv = tid >> 6;
    const float* r = S + (size_t)bid * L;
    float s0 = r[tid], s1 = r[tid + 256];
    float m = fmaxf(s0, s1);
#pragma unroll
    for (int o = 32; o > 0; o >>= 1) m = fmaxf(m, __shfl_down(m, o));
    if (lane == 0) red[wv] = m;
    __syncthreads();
    float bm = fmaxf(fmaxf(red[0], red[1]), fmaxf(red[2], red[3]));
    __syncthreads();
    float e = __expf(s0 - bm) + __expf(s1 - bm);
#pragma unroll
    for (int o = 32; o > 0; o >>= 1) e += __shfl_down(e, o);
    if (lane == 0) red[wv] = e;
    __syncthreads();
    if (tid == 0) { rmax[bid] = bm; rsum[bid] = red[0] + red[1] + red[2] + red[3]; }
  } else {
    float (*pm)[64] = (float(*)[64])smem;
    float (*ps)[64] = (float(*)[64])(smem + 1024);
    int cid = bid - B * M;
    int b = cid >> 3, ly = cid & 7;
    int w = tid >> 6, lane = tid & 63;
    int l = ly * 64 + lane;
    int nb = gcnt[b];
    const float* Sb = S + (size_t)b * M * L;
    int m0 = w * 32, m1 = min(m0 + 32, nb);
    float cm = -1e30f, cs = 0.f;
    for (int m = m0; m < m1; ++m) {
      float s = Sb[(size_t)m * L + l];
      if (s > cm) { cs = cs * __expf(cm - s) + 1.f; cm = s; }
      else cs += __expf(s - cm);
    }
    pm[w][lane] = cm; ps[w][lane] = cs;
    __syncthreads();
    if (w == 0) {
      float CM = -1e30f;
#pragma unroll
      for (int j = 0; j < 4; ++j) CM = fmaxf(CM, pm[j][lane]);
      float CS = 0.f;
#pragma unroll
      for (int j = 0; j < 4; ++j) CS += ps[j][lane] * __expf(pm[j][lane] - CM);
      cmaxv[b * L + l] = CM; csumv[b * L + l] = CS;
    }
  }
}

__device__ void d_cross(const float* S, const float* rmax, const float* rsum,
                        const float* cmaxv, const float* csumv, const int* gcnt,
                        float* wv, float* t2gcol, int bid, int tid, char* smem) {
  if (bid < 256) {
    float* rm = (float*)smem;               // 128
    float* ri = (float*)(smem + 512);       // 128
    float (*pw)[64] = (float(*)[64])(smem + 1024);
    int b = bid >> 3, ly = bid & 7;
    int w = tid >> 6, lane = tid & 63;
    if (tid < M) { rm[tid] = rmax[b * M + tid]; ri[tid] = 1.f / rsum[b * M + tid]; }
    __syncthreads();
    int l = ly * 64 + lane;
    int nb = gcnt[b];
    const float* Sb = S + (size_t)b * M * L;
    int m0 = w * 32, m1 = min(m0 + 32, nb);
    float wp = 0.f;
    for (int m = m0; m < m1; ++m)
      wp += __expf(Sb[(size_t)m * L + l] - rm[m]) * ri[m];
    pw[w][lane] = wp;
    __syncthreads();
    if (w == 0)
      wv[b * L + l] = pw[0][lane] + pw[1][lane] + pw[2][lane] + pw[3][lane];
  } else {
    float* red = (float*)smem;
    int bm = bid - 256;
    int b = bm >> 7, m = bm & 127;
    int lane = tid & 63, w = tid >> 6;
    int nb = gcnt[b];
    float acc = 0.f;
    if (m < nb) {
      const float* r = S + (size_t)bm * L;
      const float* cm = cmaxv + b * L;
      const float* cs = csumv + b * L;
      acc = __expf(r[tid] - cm[tid]) / cs[tid]
          + __expf(r[tid + 256] - cm[tid + 256]) / cs[tid + 256];
    }
#pragma unroll
    for (int o = 32; o > 0; o >>= 1) acc += __shfl_down(acc, o);
    if (lane == 0) red[w] = acc;
    __syncthreads();
    if (tid == 0) t2gcol[bm] = red[0] + red[1] + red[2] + red[3];
  }
}

// Vectorized pooled: bid = b*10 + seg. seg<8: 64 l's of wv*text; seg 8..9: 64 m's of t2gcol*xp.
__device__ void d_pooled(const float* wv, const float* t2gcol, const unsigned short* Tpk,
                         const unsigned short* xp, const int* gcnt, float* pooled,
                         int bid, int tid, char* smem) {
  float* lred = (float*)smem;
  float* wbuf = (float*)(smem + 3072);
  int b = bid / 10, seg = bid - b * 10;
  int chunk = tid % 96, half = tid / 96;
  int d = chunk * 8;
  float acc[8];
#pragma unroll
  for (int j = 0; j < 8; ++j) acc[j] = 0.f;
  if (tid < 64) {
    wbuf[tid] = (seg < 8) ? wv[b * L + seg * 64 + tid]
                          : t2gcol[b * M + (seg - 8) * 64 + tid];
  }
  __syncthreads();
  if (half < 2) {
    if (seg < 8) {
      int pbase = b * 32 + seg * 4;
      size_t cbase = ((size_t)(d >> 5)) << 9;
      int coff = ((d & 31) >> 3) << 4;
      for (int i = 0; i < 32; ++i) {
        int l = half * 32 + i;
        const unsigned short* src =
            Tpk + (((size_t)((pbase + (l >> 4)) * 24)) << 9) + cbase +
            (size_t)(coff + (l & 15)) * 8;
        fma8(acc, wbuf[l], *(const uint4*)src);
      }
    } else {
      const unsigned short* Xb = xp + (size_t)b * M * D + d;
      int m0 = (seg - 8) * 64;
      for (int i = 0; i < 32; ++i) {
        int mm = half * 32 + i;
        fma8(acc, wbuf[mm], *(const uint4*)&Xb[(size_t)(m0 + mm) * D]);
      }
    }
  }
  if (half == 1) {
#pragma unroll
    for (int j = 0; j < 8; ++j) lred[chunk * 8 + j] = acc[j];
  }
  __syncthreads();
  if (half == 0) {
    float inv = 1.f / ((float)gcnt[b] + 512.f);
#pragma unroll
    for (int j = 0; j < 8; ++j)
      atomicAdd(&pooled[(size_t)b * D + d + j], (acc[j] + lred[chunk * 8 + j]) * inv);
  }
}

__device__ void d_atom(const float* xgacc, const int* gcnt, const unsigned short* AwPk,
                       float* gpre, int bid, int tid) {
  int w = tid >> 6, lane = tid & 63;
  int q = lane >> 4, t = lane & 15;
  int nbase = bid * 64 + w * 16;
  int pb = nbase >> 4;
  int n0 = gcnt[t], n1 = gcnt[16 + t];
  float inv0 = 1.f / (float)(n0 > 1 ? n0 : 1);
  float inv1 = 1.f / (float)(n1 > 1 ? n1 : 1);
  f32x4 acc[2];
  acc[0] = (f32x4){0.f, 0.f, 0.f, 0.f};
  acc[1] = (f32x4){0.f, 0.f, 0.f, 0.f};
  for (int kk = 0; kk < 24; ++kk) {
    const float* s0 = xgacc + (size_t)t * D + kk * 32 + q * 8;
    const float* s1 = xgacc + (size_t)(16 + t) * D + kk * 32 + q * 8;
    union { unsigned short v[8]; bf16x8 f; } a0, a1;
#pragma unroll
    for (int j = 0; j < 8; ++j) { a0.v[j] = f2bf(s0[j] * inv0); a1.v[j] = f2bf(s1[j] * inv1); }
    bf16x8 bv = *(const bf16x8*)(AwPk + (((size_t)(pb * 24 + kk)) << 9) + (lane << 3));
    acc[0] = mfma16(a0.f, bv, acc[0]);
    acc[1] = mfma16(a1.f, bv, acc[1]);
  }
#pragma unroll
  for (int mi = 0; mi < 2; ++mi)
#pragma unroll
    for (int r = 0; r < 4; ++r) {
      int row = mi * 16 + q * 4 + r;
      gpre[(size_t)row * D + nbase + t] = acc[mi][r];
    }
}

// ================= global kernels =================

__global__ void k_init(int* cnt, int* cursor, int* gcnt, float* pooled, float* xgacc,
                       const unsigned short* __restrict__ t,
                       const unsigned int* __restrict__ e, int* __restrict__ flags) {
  int i = blockIdx.x * 256 + threadIdx.x;
  if (i < NNODES) { cnt[i] = 0; cursor[i] = 0; }
  if (i < B) gcnt[i] = 0;
  if (i < B * D) { pooled[i] = 0.f; xgacc[i] = 0.f; }
  if (blockIdx.x == 0) {
    __shared__ int r0[256];
    __shared__ unsigned r1[256];
    int tid = threadIdx.x;
    int bad = 0;
    for (int j = tid; j < 8192; j += 256) {
      unsigned short u = t[2 * j];
      unsigned ex = (u >> 7) & 0xFF;
      if (ex >= 0xC0) bad = 1;
    }
    unsigned o = 0;
    for (int j = tid; j < NEDGES / 2; j += 256) o |= e[2 * j + 1];
    r0[tid] = bad; r1[tid] = o;
    __syncthreads();
    for (int s = 128; s > 0; s >>= 1) {
      if (tid < s) { r0[tid] |= r0[tid + s]; r1[tid] |= r1[tid + s]; }
      __syncthreads();
    }
    if (tid == 0) { flags[0] = r0[0]; flags[1] = (r1[0] == 0) ? 1 : 0; }
  }
}

// pack_in (0..1215) + wpack (1216..3231) + count (3232..3327); no LDS.
__global__ __launch_bounds__(256) void k_setup2(
    const void* x_in, unsigned short* x0, unsigned short* PkA,
    const void* text, unsigned short* Tpk,
    const void* Ws, const void* Wn, const void* Aw,
    unsigned short* WsPk, unsigned short* WnPk, unsigned short* AwPk,
    const void* edst, const void* batch, int* cnt, int* gcnt,
    const int* __restrict__ flags) {
  int bid = blockIdx.x, tid = threadIdx.x;
  if (bid < 1216) {
    int f = flags[0];
    if (bid < NNODES / 16) d_pack_in(x_in, x0, PkA, bid, tid, f);
    else d_pack_in(text, nullptr, Tpk, bid - NNODES / 16, tid, f);
  } else if (bid < 3232) {
    d_wpack(Ws, Wn, Aw, flags[0], WsPk, WnPk, AwPk, bid - 1216, tid);
  } else {
    d_count(edst, batch, flags[1], cnt, gcnt, (bid - 3232) * 256 + tid);
  }
}

__global__ void k_scan(const int* __restrict__ cnt, int* __restrict__ rowstart) {
  __shared__ int a[NNODES], b[NNODES];
  int tid = threadIdx.x;
  for (int i = tid; i < NNODES; i += 1024) a[i] = cnt[i];
  __syncthreads();
  int* s = a; int* d = b;
  for (int off = 1; off < NNODES; off <<= 1) {
    for (int i = tid; i < NNODES; i += 1024)
      d[i] = s[i] + (i >= off ? s[i - off] : 0);
    __syncthreads();
    int* t = s; s = d; d = t;
  }
  for (int i = tid; i < NNODES; i += 1024) rowstart[i + 1] = s[i];
  if (tid == 0) rowstart[0] = 0;
}

__global__ void k_scatter(const void* __restrict__ esrc, const void* __restrict__ edst,
                          const int* __restrict__ flags, const int* __restrict__ rowstart,
                          int* __restrict__ cursor, int* __restrict__ csr) {
  int w = flags[1];
  int i = blockIdx.x * 256 + threadIdx.x;
  if (i < NEDGES) {
    int dd = ldi(edst, i, w);
    int pos = atomicAdd(&cursor[dd], 1);
    csr[rowstart[dd] + pos] = ldi(esrc, i, w);
  }
}

__global__ __launch_bounds__(256) void k_msgp(
    const unsigned short* x, const int* cnt, const int* rowstart, const int* csr,
    unsigned short* Mpk) {
  d_msg(x, cnt, rowstart, csr, Mpk, blockIdx.x, threadIdx.x);
}

// XCD-bijective swizzles (grid%8==0 in both uses).
__device__ __forceinline__ void gemm_map(int g, int& bx, int& by) {
  int gs = (g % 8) * 72 + g / 8;   // 576 = 8*72; same-bx blocks land on one XCD
  bx = gs / 12; by = gs % 12;
}
__device__ __forceinline__ void sc_map(int g, int& bx, int& by, int& bz) {
  int gs = (g % 8) * 64 + g / 8;   // 512 = 8*64; same-bz blocks land on one XCD
  bx = gs & 1; by = (gs >> 1) & 7; bz = gs >> 4;
}

__global__ __launch_bounds__(256) void k_gemm(
    const unsigned short* Apk, const unsigned short* Mpk,
    const unsigned short* WsPk, const unsigned short* WnPk,
    const void* bias, unsigned long bias_off, const int* flags, unsigned short* Y) {
  int bx, by; gemm_map(blockIdx.x, bx, by);
  d_gemm(Apk, Mpk, WsPk, WnPk, bias, bias_off, flags[0], Y, bx, by, threadIdx.x);
}

// pack (0..packN-1) + xp_pack (packN..packN+255)
__global__ __launch_bounds__(256) void k_postg(
    const unsigned short* Y, unsigned short* Npk, int packN,
    const void* pidx, const int* flags, const int* gcnt,
    unsigned short* xp, unsigned short* XpPk, float* xgacc) {
  extern __shared__ char smem[];
  int bid = blockIdx.x, tid = threadIdx.x;
  if (bid < packN) d_pack(Y, Npk, bid, tid);
  else d_xp(Y, pidx, flags[1], gcnt, xp, XpPk, xgacc, bid - packN, tid, smem);
}

// scores (0..511) + msg(next) (512..512+msgN-1); no LDS in either role.
__global__ __launch_bounds__(256) void k_scmsg(
    const unsigned short* XpPk, const unsigned short* Tpk, float* S,
    int msgN, const unsigned short* x, const int* cnt, const int* rowstart,
    const int* csr, unsigned short* Mpk) {
  int bid = blockIdx.x, tid = threadIdx.x;
  if (bid < 512) {
    int bx, by, bz; sc_map(bid, bx, by, bz);
    d_scores(XpPk, Tpk, S, bx, by, bz, tid);
  } else d_msg(x, cnt, rowstart, csr, Mpk, bid - 512, tid);
}

// stats (0..4351) + gemm(next) (4352..4352+gemmN-1); 2KB smem for stats only.
__global__ __launch_bounds__(256) void k_stgemm(
    const float* S, const int* gcnt, float* rmax, float* rsum, float* cmaxv, float* csumv,
    int gemmN, const unsigned short* Apk, const unsigned short* Mpk,
    const unsigned short* WsPk, const unsigned short* WnPk,
    const void* bias, unsigned long bias_off, const int* flags, unsigned short* Y) {
  extern __shared__ char smem[];
  int bid = blockIdx.x, tid = threadIdx.x;
  if (bid < 4352) d_stats(S, gcnt, rmax, rsum, cmaxv, csumv, bid, tid, smem);
  else {
    int bx, by; gemm_map(bid - 4352, bx, by);
    d_gemm(Apk, Mpk, WsPk, WnPk, bias, bias_off, flags[0], Y, bx, by, tid);
  }
}

// cross (0..4351) + pack(next) + xp_pack(next)
__global__ __launch_bounds__(256) void k_crpostg(
    const float* S, const float* rmax, const float* rsum, const float* cmaxv,
    const float* csumv, const int* gcnt, float* wv, float* t2gcol,
    int packN, int xpN, const unsigned short* Y, unsigned short* Npk,
    const void* pidx, const int* flags, unsigned short* xp, unsigned short* XpPk,
    float* xgacc) {
  extern __shared__ char smem[];
  int bid = blockIdx.x, tid = threadIdx.x;
  if (bid < 4352) d_cross(S, rmax, rsum, cmaxv, csumv, gcnt, wv, t2gcol, bid, tid, smem);
  else {
    int r = bid - 4352;
    if (r < packN) d_pack(Y, Npk, r, tid);
    else d_xp(Y, pidx, flags[1], gcnt, xp, XpPk, xgacc, r - packN, tid, smem);
  }
}

// pooled (0..319) + scores(next) (320..320+scN-1) + msg (then msgN) + atom (then atomN)
__global__ __launch_bounds__(256) void k_plscmsg(
    const float* wv, const float* t2gcol, const unsigned short* Tpk,
    const unsigned short* xpL, const int* gcnt, float* pooled,
    int scN, const unsigned short* XpPk, float* S,
    int msgN, const unsigned short* x, const int* cnt, const int* rowstart,
    const int* csr, unsigned short* Mpk,
    int atomN, const float* xgacc, const unsigned short* AwPk, float* gpre) {
  extern __shared__ char smem[];
  int bid = blockIdx.x, tid = threadIdx.x;
  if (bid < 320) { d_pooled(wv, t2gcol, Tpk, xpL, gcnt, pooled, bid, tid, smem); return; }
  int r = bid - 320;
  if (r < scN) {
    int bx, by, bz; sc_map(r, bx, by, bz);
    d_scores(XpPk, Tpk, S, bx, by, bz, tid); return;
  }
  r -= scN;
  if (r < msgN) { d_msg(x, cnt, rowstart, csr, Mpk, r, tid); return; }
  d_atom(xgacc, gcnt, AwPk, gpre, r - msgN, tid);
}

__global__ __launch_bounds__(256) void k_final(
    const unsigned short* __restrict__ Tpk, const float* __restrict__ gpre,
    const float* __restrict__ pooled, const void* __restrict__ ab,
    const void* __restrict__ dmask, const void* __restrict__ gmask,
    const void* __restrict__ remb, const int* __restrict__ flags,
    void* __restrict__ out) {
  int f = flags[0];
  int b = blockIdx.x, tid = threadIdx.x;
  float dm = ldf(dmask, b, f);
  float gm = ldf(gmask, b, f);
  float dg = dm * gm;
  size_t base = (size_t)b * 2304;
#pragma unroll
  for (int j = 0; j < 3; ++j) {
    int d = tid + j * 256;
    float z = ldf(remb, d, f);
    float tv = pk_read(Tpk, b * 32, 0, d);
    float o0 = tv * dm + (1.f - dm) * z;
    float gv = tanhf(gpre[(size_t)b * D + d] + ldf(ab, d, f));
    float o1 = gv * gm + (1.f - gm) * z;
    float p = pooled[(size_t)b * D + d] * (1.f / 3.f);
    float o2 = p * dg + (1.f - dg) * z;
    if (f) {
      float* of = (float*)out;
      of[base + d] = o0; of[base + 768 + d] = o1; of[base + 1536 + d] = o2;
    } else {
      unsigned short* ob = (unsigned short*)out;
      ob[base + d] = f2bf(o0); ob[base + 768 + d] = f2bf(o1); ob[base + 1536 + d] = f2bf(o2);
    }
  }
}

extern "C" void kernel_launch(void* const* d_in, const int* in_sizes, int n_in,
                              void* d_out, int out_size, void* d_ws, size_t ws_size,
                              hipStream_t stream) {
  const void* x_in  = d_in[0];
  const void* text  = d_in[1];
  const void* dmask = d_in[2];
  const void* gmask = d_in[3];
  const void* gws   = d_in[4];
  const void* gwn   = d_in[5];
  const void* gb    = d_in[6];
  const void* aw    = d_in[7];
  const void* ab    = d_in[8];
  const void* remb  = d_in[9];
  const void* batch = d_in[10];
  const void* pidx  = d_in[11];
  const void* esrc  = d_in[13];
  const void* edst  = d_in[14];

  char* wsp = (char*)d_ws;
  size_t off = 0;
  auto carve = [&](size_t bytes) -> void* {
    void* p = wsp + off;
    off += (bytes + 255) & ~(size_t)255;
    return p;
  };
  int* flags = (int*)carve(2 * 4);
  unsigned short* x0    = (unsigned short*)carve((size_t)NNODES * D * 2);
  unsigned short* xA    = (unsigned short*)carve((size_t)NNODES * D * 2);
  unsigned short* xB    = (unsigned short*)carve((size_t)NNODES * D * 2);
  unsigned short* PkA   = (unsigned short*)carve((size_t)NNODES * D * 2);
  unsigned short* PkB   = (unsigned short*)carve((size_t)NNODES * D * 2);
  unsigned short* Mpk   = (unsigned short*)carve((size_t)NNODES * D * 2);
  unsigned short* Tpk   = (unsigned short*)carve((size_t)B * L * D * 2);
  unsigned short* WsPk  = (unsigned short*)carve((size_t)3 * D * D * 2);
  unsigned short* WnPk  = (unsigned short*)carve((size_t)3 * D * D * 2);
  unsigned short* AwPk  = (unsigned short*)carve((size_t)D * D * 2);
  unsigned short* xpA   = (unsigned short*)carve((size_t)B * M * D * 2);
  unsigned short* xpB   = (unsigned short*)carve((size_t)B * M * D * 2);
  unsigned short* XpPkA = (unsigned short*)carve((size_t)B * M * D * 2);
  unsigned short* XpPkB = (unsigned short*)carve((size_t)B * M * D * 2);
  float* xgacc   = (float*)carve((size_t)B * D * 4);
  float* gpre    = (float*)carve((size_t)B * D * 4);
  float* S       = (float*)carve((size_t)B * M * L * 4);
  float* rmax    = (float*)carve((size_t)B * M * 4);
  float* rsum    = (float*)carve((size_t)B * M * 4);
  float* wv      = (float*)carve((size_t)B * L * 4);
  float* cmaxv   = (float*)carve((size_t)B * L * 4);
  float* csumv   = (float*)carve((size_t)B * L * 4);
  float* t2gcol  = (float*)carve((size_t)B * M * 4);
  float* pooled  = (float*)carve((size_t)B * D * 4);
  int* cnt      = (int*)carve((size_t)NNODES * 4);
  int* rowstart = (int*)carve((size_t)(NNODES + 1) * 4);
  int* cursor   = (int*)carve((size_t)NNODES * 4);
  int* gcnt     = (int*)carve((size_t)B * 4);
  int* csr      = (int*)carve((size_t)NEDGES * 4);

  const size_t DD = (size_t)D * D;

  k_init<<<96, 256, 0, stream>>>(cnt, cursor, gcnt, pooled, xgacc,
                                 (const unsigned short*)text, (const unsigned int*)edst, flags);
  k_setup2<<<3328, 256, 0, stream>>>(x_in, x0, PkA, text, Tpk, gws, gwn, aw,
                                     WsPk, WnPk, AwPk, edst, batch, cnt, gcnt, flags);
  k_scan<<<1, 1024, 0, stream>>>(cnt, rowstart);
  k_scatter<<<96, 256, 0, stream>>>(esrc, edst, flags, rowstart, cursor, csr);

  // ---- pipelined layer schedule ----
  k_msgp<<<192, 256, 0, stream>>>(x0, cnt, rowstart, csr, Mpk);
  k_gemm<<<576, 256, 0, stream>>>(PkA, Mpk, WsPk, WnPk, gb, 0, flags, xA);
  k_postg<<<448, 256, 24832, stream>>>(xA, PkB, 192, pidx, flags, gcnt, xpA, XpPkA, nullptr);
  k_scmsg<<<704, 256, 0, stream>>>(XpPkA, Tpk, S, 192, xA, cnt, rowstart, csr, Mpk);
  k_stgemm<<<4928, 256, 2048, stream>>>(S, gcnt, rmax, rsum, cmaxv, csumv,
                                        576, PkB, Mpk, WsPk + DD, WnPk + DD, gb, D, flags, xB);
  k_crpostg<<<4800, 256, 24832, stream>>>(S, rmax, rsum, cmaxv, csumv, gcnt, wv, t2gcol,
                                          192, 256, xB, PkA, pidx, flags, xpB, XpPkB, nullptr);
  k_plscmsg<<<1024, 256, 4096, stream>>>(wv, t2gcol, Tpk, xpA, gcnt, pooled,
                                         512, XpPkB, S, 192, xB, cnt, rowstart, csr, Mpk,
                                         0, nullptr, nullptr, nullptr);
  k_stgemm<<<4928, 256, 2048, stream>>>(S, gcnt, rmax, rsum, cmaxv, csumv,
                                        576, PkA, Mpk, WsPk + 2 * DD, WnPk + 2 * DD,
                                        gb, 2 * D, flags, xA);
  k_crpostg<<<4608, 256, 24832, stream>>>(S, rmax, rsum, cmaxv, csumv, gcnt, wv, t2gcol,
                                          0, 256, xA, nullptr, pidx, flags, xpA, XpPkA, xgacc);
  k_plscmsg<<<832, 256, 4096, stream>>>(wv, t2gcol, Tpk, xpB, gcnt, pooled,
                                        512, XpPkA, S, 0, nullptr, nullptr, nullptr,
                                        nullptr, nullptr, 0, nullptr, nullptr, nullptr);
  k_stgemm<<<4352, 256, 2048, stream>>>(S, gcnt, rmax, rsum, cmaxv, csumv,
                                        0, nullptr, nullptr, nullptr, nullptr,
                                        nullptr, 0, flags, nullptr);
  k_crpostg<<<4352, 256, 2048, stream>>>(S, rmax, rsum, cmaxv, csumv, gcnt, wv, t2gcol,
                                         0, 0, nullptr, nullptr, pidx, flags,
                                         nullptr, nullptr, nullptr);
  k_plscmsg<<<332, 256, 4096, stream>>>(wv, t2gcol, Tpk, xpA, gcnt, pooled,
                                        0, nullptr, nullptr, 0, nullptr, nullptr, nullptr,
                                        nullptr, nullptr, 12, xgacc, AwPk, gpre);
  k_final<<<32, 256, 0, stream>>>(Tpk, gpre, pooled, ab, dmask, gmask, remb, flags, d_out);
}

// Round 9
// 411.025 us; speedup vs baseline: 1.2031x; 1.0247x over previous
//
#include <hip/hip_runtime.h>

#define D 768
#define B 32
#define L 512
#define M 128
#define NNODES 3072
#define NEDGES 24576

using bf16x8 = __attribute__((ext_vector_type(8))) short;
using f32x4  = __attribute__((ext_vector_type(4))) float;

__device__ __forceinline__ float bf2f(unsigned short u) {
  union { unsigned int i; float f; } v; v.i = ((unsigned int)u) << 16; return v.f;
}
__device__ __forceinline__ unsigned short f2bf(float f) {
  union { float f; unsigned int i; } v; v.f = f;
  unsigned int x = v.i;
  return (unsigned short)((x + 0x7FFFu + ((x >> 16) & 1u)) >> 16);
}
__device__ __forceinline__ float ldf(const void* p, size_t i, int f32) {
  return f32 ? ((const float*)p)[i] : bf2f(((const unsigned short*)p)[i]);
}
__device__ __forceinline__ int ldi(const void* p, size_t i, int w64) {
  return w64 ? (int)((const long long*)p)[i] : ((const int*)p)[i];
}
__device__ __forceinline__ f32x4 mfma16(bf16x8 a, bf16x8 b, f32x4 c) {
  return __builtin_amdgcn_mfma_f32_16x16x32_bf16(a, b, c, 0, 0, 0);
}

// Packed fragment layout for row-major [R x 768] bf16:
//   (row,k) -> panel p=row/16, kk=k/32, lane=((k%32)/8)*16+row%16, e=k%8
// A wave's MFMA fragment for (panel,kk) is the contiguous 16B at
//   base + ((panel*24+kk)<<9) + lane*8  -> direct global->register loads.
__device__ __forceinline__ float pk_read(const unsigned short* P, int p, int l, int d) {
  return bf2f(P[(((size_t)(p * 24 + (d >> 5))) << 9) + ((((d & 31) >> 3) << 4) + l) * 8 + (d & 7)]);
}

__device__ __forceinline__ void fma8(float* acc, float w, uint4 v) {
  unsigned xs[4] = {v.x, v.y, v.z, v.w};
#pragma unroll
  for (int j = 0; j < 4; ++j) {
    acc[2 * j]     += w * bf2f((unsigned short)(xs[j] & 0xFFFFu));
    acc[2 * j + 1] += w * bf2f((unsigned short)(xs[j] >> 16));
  }
}

__device__ __forceinline__ void acc12(float* a, const uint2* u) {
#pragma unroll
  for (int j = 0; j < 3; ++j) {
    a[j * 4 + 0] += bf2f((unsigned short)(u[j].x & 0xFFFFu));
    a[j * 4 + 1] += bf2f((unsigned short)(u[j].x >> 16));
    a[j * 4 + 2] += bf2f((unsigned short)(u[j].y & 0xFFFFu));
    a[j * 4 + 3] += bf2f((unsigned short)(u[j].y >> 16));
  }
}

// ================= device role bodies =================

// LDS-free pack: packed uint4 (p,kk,lane) == source row p*16+(lane&15),
// cols kk*32+(lane>>4)*8 .. +8 (8 consecutive source elements).
__device__ void d_pack_in(const void* src, unsigned short* rows, unsigned short* dst,
                          int p, int tid, int f) {
  unsigned short* pb = dst + (size_t)p * 12288;
#pragma unroll
  for (int j = 0; j < 6; ++j) {
    int odx = j * 256 + tid;
    int kk = odx >> 6, lanep = odx & 63;
    int q = lanep >> 4, r16 = lanep & 15;
    int row = p * 16 + r16, col0 = kk * 32 + q * 8;
    size_t sbase = (size_t)row * 768 + col0;
    union { unsigned short v[8]; uint4 qv; } u;
    if (f) {
      const float* sp = (const float*)src + sbase;
      float4 v0 = *(const float4*)sp;
      float4 v1 = *(const float4*)(sp + 4);
      u.v[0] = f2bf(v0.x); u.v[1] = f2bf(v0.y); u.v[2] = f2bf(v0.z); u.v[3] = f2bf(v0.w);
      u.v[4] = f2bf(v1.x); u.v[5] = f2bf(v1.y); u.v[6] = f2bf(v1.z); u.v[7] = f2bf(v1.w);
    } else {
      u.qv = *(const uint4*)((const unsigned short*)src + sbase);
    }
    if (rows) *(uint4*)&rows[sbase] = u.qv;
    *(uint4*)&pb[(size_t)odx * 8] = u.qv;
  }
}

// LDS-free wpack: packed (pG,kk,lane,e) = W[kk*32+(lane>>4)*8+e][pG*16+(lane&15)].
__device__ void d_wpack(const void* Ws, const void* Wn, const void* Aw, int f,
                        unsigned short* WsPk, unsigned short* WnPk, unsigned short* AwPk,
                        int r0, int tid) {
  int z = r0 / 288, rem = r0 % 288;
  int nblk = rem % 12, kk = rem / 12;
  const void* src; unsigned short* dst; size_t zoff;
  if (z < 3)      { src = Ws; zoff = (size_t)z * D * D;       dst = WsPk + zoff; }
  else if (z < 6) { src = Wn; zoff = (size_t)(z - 3) * D * D; dst = WnPk + zoff; }
  else            { src = Aw; zoff = 0;                       dst = AwPk; }
  int pl = tid >> 6, lane = tid & 63;
  int pG = nblk * 4 + pl;
  int k0 = kk * 32 + ((lane >> 4) << 3);
  int n  = nblk * 64 + pl * 16 + (lane & 15);
  union { unsigned short v[8]; uint4 q; } u;
  if (f) {
    const float* sp = (const float*)src + zoff + (size_t)k0 * D + n;
#pragma unroll
    for (int e = 0; e < 8; ++e) u.v[e] = f2bf(sp[(size_t)e * D]);
  } else {
    const unsigned short* sp = (const unsigned short*)src + zoff + (size_t)k0 * D + n;
#pragma unroll
    for (int e = 0; e < 8; ++e) u.v[e] = sp[(size_t)e * D];
  }
  *(uint4*)&dst[(((size_t)(pG * 24 + kk)) << 9) + lane * 8] = u.q;
}

// count: edge atomics stay; gcnt uses sorted-run ballot (batch is sorted).
__device__ void d_count(const void* edst, const void* batch, int w,
                        int* cnt, int* gcnt, int i) {
  if (i < NEDGES) atomicAdd(&cnt[ldi(edst, i, w)], 1);
  if (i < NNODES) {
    int b = ldi(batch, i, w);
    int lane = i & 63;
    int prev = __shfl_up(b, 1);
    bool first = (lane == 0) || (prev != b);
    unsigned long long bm = __ballot(first ? 1 : 0);
    if (first) {
      unsigned long long higher = (lane < 63) ? (bm >> (lane + 1)) : 0ULL;
      int next = higher ? (lane + __ffsll((long long)higher)) : 64;
      atomicAdd(&gcnt[b], next - lane);
    }
  }
}

// msg: reads ROW-MAJOR x (coalesced full rows), writes packed Mpk.
// 4-row concurrent: 12 independent loads in flight per edge-iteration,
// deg is wave-uniform so all branches are uniform.
__device__ void d_msg(const unsigned short* x, const int* cnt, const int* rowstart,
                      const int* csr, unsigned short* Mpk, int p, int tid) {
  int w = tid >> 6, lane = tid & 63;
  unsigned short* pb = Mpk + (size_t)p * 12288;
  int deg[4], base[4];
  float a[4][12];
#pragma unroll
  for (int r4 = 0; r4 < 4; ++r4) {
    int n = p * 16 + w * 4 + r4;
    deg[r4] = cnt[n]; base[r4] = rowstart[n];
#pragma unroll
    for (int j = 0; j < 12; ++j) a[r4][j] = 0.f;
  }
  int dmax = max(max(deg[0], deg[1]), max(deg[2], deg[3]));
  for (int e = 0; e < dmax; ++e) {
    uint2 u[4][3];
#pragma unroll
    for (int r4 = 0; r4 < 4; ++r4) {
      if (e < deg[r4]) {
        const uint2* xr = (const uint2*)(x + (size_t)csr[base[r4] + e] * D);
        u[r4][0] = xr[lane]; u[r4][1] = xr[lane + 64]; u[r4][2] = xr[lane + 128];
      }
    }
#pragma unroll
    for (int r4 = 0; r4 < 4; ++r4)
      if (e < deg[r4]) acc12(a[r4], u[r4]);
  }
#pragma unroll
  for (int r4 = 0; r4 < 4; ++r4) {
    int rA = w * 4 + r4;
    float inv = 1.0f / (float)(deg[r4] > 1 ? deg[r4] : 1);
#pragma unroll
    for (int j = 0; j < 3; ++j) {
      int d0 = (lane + j * 64) * 4;
      int kk = d0 >> 5, q = (d0 >> 3) & 3, e0 = d0 & 7;
      uint2 wv;
      wv.x = (unsigned int)f2bf(a[r4][j * 4 + 0] * inv)
           | ((unsigned int)f2bf(a[r4][j * 4 + 1] * inv) << 16);
      wv.y = (unsigned int)f2bf(a[r4][j * 4 + 2] * inv)
           | ((unsigned int)f2bf(a[r4][j * 4 + 3] * inv) << 16);
      *(uint2*)&pb[kk * 512 + (q * 16 + rA) * 8 + e0] = wv;
    }
  }
}

// BARRIER-FREE GEMM: direct global->register fragment streams (packed
// layout, lane-contiguous 16B). No LDS, no sync. Epilogue dual-writes:
// Y row-major (for gathers) and optionally Ypk packed (for next-layer
// MFMA A-operand) — identical rounded bf16 bits, deletes the pack stage.
__device__ void d_gemm(const unsigned short* Xpk, const unsigned short* Mpk,
                       const unsigned short* WsPk, const unsigned short* WnPk,
                       const void* bias, size_t bias_off, int f,
                       unsigned short* Y, unsigned short* Ypk, int bx, int by, int tid) {
  int wave = tid >> 6, lane = tid & 63;
  int q = lane >> 4, t = lane & 15;
  int wm = wave >> 1, wn = wave & 1;
  const int PAN = 24 << 9;   // panel stride in ushorts
  f32x4 acc[2][2];
#pragma unroll
  for (int mi = 0; mi < 2; ++mi)
#pragma unroll
    for (int ni = 0; ni < 2; ++ni)
      acc[mi][ni] = (f32x4){0.f, 0.f, 0.f, 0.f};
  size_t aoff = (((size_t)((bx * 4 + wm * 2) * 24)) << 9) + lane * 8;
  size_t boff = (((size_t)((by * 4 + wn * 2) * 24)) << 9) + lane * 8;
  {
    const unsigned short* A = Xpk + aoff;
    const unsigned short* Bp = WsPk + boff;
#pragma unroll 4
    for (int kk = 0; kk < 24; ++kk) {
      bf16x8 a0 = *(const bf16x8*)(A + kk * 512);
      bf16x8 a1 = *(const bf16x8*)(A + kk * 512 + PAN);
      bf16x8 b0 = *(const bf16x8*)(Bp + kk * 512);
      bf16x8 b1 = *(const bf16x8*)(Bp + kk * 512 + PAN);
      acc[0][0] = mfma16(a0, b0, acc[0][0]);
      acc[0][1] = mfma16(a0, b1, acc[0][1]);
      acc[1][0] = mfma16(a1, b0, acc[1][0]);
      acc[1][1] = mfma16(a1, b1, acc[1][1]);
    }
  }
  {
    const unsigned short* A = Mpk + aoff;
    const unsigned short* Bp = WnPk + boff;
#pragma unroll 4
    for (int kk = 0; kk < 24; ++kk) {
      bf16x8 a0 = *(const bf16x8*)(A + kk * 512);
      bf16x8 a1 = *(const bf16x8*)(A + kk * 512 + PAN);
      bf16x8 b0 = *(const bf16x8*)(Bp + kk * 512);
      bf16x8 b1 = *(const bf16x8*)(Bp + kk * 512 + PAN);
      acc[0][0] = mfma16(a0, b0, acc[0][0]);
      acc[0][1] = mfma16(a0, b1, acc[0][1]);
      acc[1][0] = mfma16(a1, b0, acc[1][0]);
      acc[1][1] = mfma16(a1, b1, acc[1][1]);
    }
  }
#pragma unroll
  for (int ni = 0; ni < 2; ++ni) {
    int col = by * 64 + wn * 32 + ni * 16 + t;
    float bv = ldf(bias, bias_off + col, f);
    int kkc = col >> 5, cq = (col >> 3) & 3, ec = col & 7;
#pragma unroll
    for (int mi = 0; mi < 2; ++mi) {
      unsigned short us[4];
#pragma unroll
      for (int r = 0; r < 4; ++r) {
        int row = bx * 64 + wm * 32 + mi * 16 + q * 4 + r;
        float v = acc[mi][ni][r] + bv;
        us[r] = f2bf(v > 0.f ? v : 0.f);
        Y[(size_t)row * D + col] = us[r];
      }
      if (Ypk) {
        int pOut = bx * 4 + wm * 2 + mi;
        unsigned short* ob = Ypk + (size_t)pOut * 12288 + kkc * 512 + ec;
#pragma unroll
        for (int r = 0; r < 4; ++r)
          ob[(cq * 16 + q * 4 + r) * 8] = us[r];
      }
    }
  }
}

__device__ void d_xp(const unsigned short* Xn, const void* pidx, int w64,
                     const int* gcnt, unsigned short* xp, unsigned short* XpPk,
                     float* xgacc, int p, int tid, char* smem) {
  unsigned short* rows = (unsigned short*)smem;   // 16*776
  int r = tid >> 4, c16 = tid & 15;
  int bm = p * 16 + r;
  int b = bm >> 7, m = bm & 127;
  int nb = gcnt[b];
  uint4* dl = (uint4*)&rows[r * 776];
  uint4 v[6];
  if (m < nb) {
    const uint4* srcr = (const uint4*)(Xn + (size_t)ldi(pidx, bm, w64) * D);
#pragma unroll
    for (int j = 0; j < 6; ++j) v[j] = srcr[c16 + j * 16];
  } else {
    uint4 z = {0u, 0u, 0u, 0u};
#pragma unroll
    for (int j = 0; j < 6; ++j) v[j] = z;
  }
#pragma unroll
  for (int j = 0; j < 6; ++j) dl[c16 + j * 16] = v[j];
  __syncthreads();
#pragma unroll
  for (int j = 0; j < 6; ++j) {
    int idx = j * 256 + tid;
    int rr = idx / 96, cc = idx % 96;
    uint4 vv = *(const uint4*)&rows[rr * 776 + cc * 8];
    *(uint4*)&xp[(size_t)(p * 16 + rr) * D + cc * 8] = vv;
  }
  unsigned short* pb = XpPk + (size_t)p * 12288;
#pragma unroll
  for (int j = 0; j < 6; ++j) {
    int odx = j * 256 + tid;
    int kk = odx >> 6, lanep = odx & 63;
    int rr = lanep & 15, cg = lanep >> 4;
    int cc = kk * 4 + cg;
    uint4 vv = *(const uint4*)&rows[rr * 776 + cc * 8];
    *(uint4*)&pb[odx * 8] = vv;
  }
  if (xgacc) {
    int bb = p >> 3;
#pragma unroll
    for (int j = 0; j < 3; ++j) {
      int d = j * 256 + tid;
      float s = 0.f;
#pragma unroll
      for (int rr = 0; rr < 16; ++rr) s += bf2f(rows[rr * 776 + d]);
      atomicAdd(&xgacc[(size_t)bb * D + d], s);
    }
  }
}

// BARRIER-FREE scores: direct global->register fragment streams, 24 kk.
__device__ void d_scores(const unsigned short* XpPk, const unsigned short* Tpk,
                         float* S, int bx, int by, int bz, int tid) {
  int wave = tid >> 6, lane = tid & 63;
  int q = lane >> 4, t = lane & 15;
  int wm = wave >> 1, wn = wave & 1;
  const int PAN = 24 << 9;
  f32x4 acc[2][2];
#pragma unroll
  for (int mi = 0; mi < 2; ++mi)
#pragma unroll
    for (int ni = 0; ni < 2; ++ni)
      acc[mi][ni] = (f32x4){0.f, 0.f, 0.f, 0.f};
  size_t aoff = (((size_t)((bz * 8 + bx * 4 + wm * 2) * 24)) << 9) + lane * 8;
  size_t boff = (((size_t)((bz * 32 + by * 4 + wn * 2) * 24)) << 9) + lane * 8;
  const unsigned short* A = XpPk + aoff;
  const unsigned short* Bp = Tpk + boff;
#pragma unroll 4
  for (int kk = 0; kk < 24; ++kk) {
    bf16x8 a0 = *(const bf16x8*)(A + kk * 512);
    bf16x8 a1 = *(const bf16x8*)(A + kk * 512 + PAN);
    bf16x8 b0 = *(const bf16x8*)(Bp + kk * 512);
    bf16x8 b1 = *(const bf16x8*)(Bp + kk * 512 + PAN);
    acc[0][0] = mfma16(a0, b0, acc[0][0]);
    acc[0][1] = mfma16(a0, b1, acc[0][1]);
    acc[1][0] = mfma16(a1, b0, acc[1][0]);
    acc[1][1] = mfma16(a1, b1, acc[1][1]);
  }
  float* Sb = S + (size_t)bz * M * L;
#pragma unroll
  for (int ni = 0; ni < 2; ++ni) {
    int col = by * 64 + wn * 32 + ni * 16 + t;
#pragma unroll
    for (int mi = 0; mi < 2; ++mi) {
#pragma unroll
      for (int r = 0; r < 4; ++r) {
        int row = bx * 64 + wm * 32 + mi * 16 + q * 4 + r;
        Sb[(size_t)row * L + col] = acc[mi][ni][r];
      }
    }
  }
}

__device__ void d_stats(const float* S, const int* gcnt, float* rmax, float* rsum,
                        float* cmaxv, float* csumv, int bid, int tid, char* smem) {
  if (bid < B * M) {
    float* red = (float*)smem;
    int lane = tid & 63, wv = tid >> 6;
    const float* r = S + (size_t)bid * L;
    float s0 = r[tid], s1 = r[tid + 256];
    float m = fmaxf(s0, s1);
#pragma unroll
    for (int o = 32; o > 0; o >>= 1) m = fmaxf(m, __shfl_down(m, o));
    if (lane == 0) red[wv] = m;
    __syncthreads();
    float bm = fmaxf(fmaxf(red[0], red[1]), fmaxf(red[2], red[3]));
    __syncthreads();
    float e = __expf(s0 - bm) + __expf(s1 - bm);
#pragma unroll
    for (int o = 32; o > 0; o >>= 1) e += __shfl_down(e, o);
    if (lane == 0) red[wv] = e;
    __syncthreads();
    if (tid == 0) { rmax[bid] = bm; rsum[bid] = red[0] + red[1] + red[2] + red[3]; }
  } else {
    float (*pm)[64] = (float(*)[64])smem;
    float (*ps)[64] = (float(*)[64])(smem + 1024);
    int cid = bid - B * M;
    int b = cid >> 3, ly = cid & 7;
    int w = tid >> 6, lane = tid & 63;
    int l = ly * 64 + lane;
    int nb = gcnt[b];
    const float* Sb = S + (size_t)b * M * L;
    int m0 = w * 32, m1 = min(m0 + 32, nb);
    float cm = -1e30f, cs = 0.f;
    for (int m = m0; m < m1; ++m) {
      float s = Sb[(size_t)m * L + l];
      if (s > cm) { cs = cs * __expf(cm - s) + 1.f; cm = s; }
      else cs += __expf(s - cm);
    }
    pm[w][lane] = cm; ps[w][lane] = cs;
    __syncthreads();
    if (w == 0) {
      float CM = -1e30f;
#pragma unroll
      for (int j = 0; j < 4; ++j) CM = fmaxf(CM, pm[j][lane]);
      float CS = 0.f;
#pragma unroll
      for (int j = 0; j < 4; ++j) CS += ps[j][lane] * __expf(pm[j][lane] - CM);
      cmaxv[b * L + l] = CM; csumv[b * L + l] = CS;
    }
  }
}

__device__ void d_cross(const float* S, const float* rmax, const float* rsum,
                        const float* cmaxv, const float* csumv, const int* gcnt,
                        float* wv, float* t2gcol, int bid, int tid, char* smem) {
  if (bid < 256) {
    float* rm = (float*)smem;               // 128
    float* ri = (float*)(smem + 512);       // 128
    float (*pw)[64] = (float(*)[64])(smem + 1024);
    int b = bid >> 3, ly = bid & 7;
    int w = tid >> 6, lane = tid & 63;
    if (tid < M) { rm[tid] = rmax[b * M + tid]; ri[tid] = 1.f / rsum[b * M + tid]; }
    __syncthreads();
    int l = ly * 64 + lane;
    int nb = gcnt[b];
    const float* Sb = S + (size_t)b * M * L;
    int m0 = w * 32, m1 = min(m0 + 32, nb);
    float wp = 0.f;
    for (int m = m0; m < m1; ++m)
      wp += __expf(Sb[(size_t)m * L + l] - rm[m]) * ri[m];
    pw[w][lane] = wp;
    __syncthreads();
    if (w == 0)
      wv[b * L + l] = pw[0][lane] + pw[1][lane] + pw[2][lane] + pw[3][lane];
  } else {
    float* red = (float*)smem;
    int bm = bid - 256;
    int b = bm >> 7, m = bm & 127;
    int lane = tid & 63, w = tid >> 6;
    int nb = gcnt[b];
    float acc = 0.f;
    if (m < nb) {
      const float* r = S + (size_t)bm * L;
      const float* cm = cmaxv + b * L;
      const float* cs = csumv + b * L;
      acc = __expf(r[tid] - cm[tid]) / cs[tid]
          + __expf(r[tid + 256] - cm[tid + 256]) / cs[tid + 256];
    }
#pragma unroll
    for (int o = 32; o > 0; o >>= 1) acc += __shfl_down(acc, o);
    if (lane == 0) red[w] = acc;
    __syncthreads();
    if (tid == 0) t2gcol[bm] = red[0] + red[1] + red[2] + red[3];
  }
}

// Vectorized pooled: bid = b*10 + seg. seg<8: 64 l's of wv*text; seg 8..9: 64 m's of t2gcol*xp.
__device__ void d_pooled(const float* wv, const float* t2gcol, const unsigned short* Tpk,
                         const unsigned short* xp, const int* gcnt, float* pooled,
                         int bid, int tid, char* smem) {
  float* lred = (float*)smem;
  float* wbuf = (float*)(smem + 3072);
  int b = bid / 10, seg = bid - b * 10;
  int chunk = tid % 96, half = tid / 96;
  int d = chunk * 8;
  float acc[8];
#pragma unroll
  for (int j = 0; j < 8; ++j) acc[j] = 0.f;
  if (tid < 64) {
    wbuf[tid] = (seg < 8) ? wv[b * L + seg * 64 + tid]
                          : t2gcol[b * M + (seg - 8) * 64 + tid];
  }
  __syncthreads();
  if (half < 2) {
    if (seg < 8) {
      int pbase = b * 32 + seg * 4;
      size_t cbase = ((size_t)(d >> 5)) << 9;
      int coff = ((d & 31) >> 3) << 4;
      for (int i = 0; i < 32; ++i) {
        int l = half * 32 + i;
        const unsigned short* src =
            Tpk + (((size_t)((pbase + (l >> 4)) * 24)) << 9) + cbase +
            (size_t)(coff + (l & 15)) * 8;
        fma8(acc, wbuf[l], *(const uint4*)src);
      }
    } else {
      const unsigned short* Xb = xp + (size_t)b * M * D + d;
      int m0 = (seg - 8) * 64;
      for (int i = 0; i < 32; ++i) {
        int mm = half * 32 + i;
        fma8(acc, wbuf[mm], *(const uint4*)&Xb[(size_t)(m0 + mm) * D]);
      }
    }
  }
  if (half == 1) {
#pragma unroll
    for (int j = 0; j < 8; ++j) lred[chunk * 8 + j] = acc[j];
  }
  __syncthreads();
  if (half == 0) {
    float inv = 1.f / ((float)gcnt[b] + 512.f);
#pragma unroll
    for (int j = 0; j < 8; ++j)
      atomicAdd(&pooled[(size_t)b * D + d + j], (acc[j] + lred[chunk * 8 + j]) * inv);
  }
}

__device__ void d_atom(const float* xgacc, const int* gcnt, const unsigned short* AwPk,
                       float* gpre, int bid, int tid) {
  int w = tid >> 6, lane = tid & 63;
  int q = lane >> 4, t = lane & 15;
  int nbase = bid * 64 + w * 16;
  int pb = nbase >> 4;
  int n0 = gcnt[t], n1 = gcnt[16 + t];
  float inv0 = 1.f / (float)(n0 > 1 ? n0 : 1);
  float inv1 = 1.f / (float)(n1 > 1 ? n1 : 1);
  f32x4 acc[2];
  acc[0] = (f32x4){0.f, 0.f, 0.f, 0.f};
  acc[1] = (f32x4){0.f, 0.f, 0.f, 0.f};
  for (int kk = 0; kk < 24; ++kk) {
    const float* s0 = xgacc + (size_t)t * D + kk * 32 + q * 8;
    const float* s1 = xgacc + (size_t)(16 + t) * D + kk * 32 + q * 8;
    union { unsigned short v[8]; bf16x8 f; } a0, a1;
#pragma unroll
    for (int j = 0; j < 8; ++j) { a0.v[j] = f2bf(s0[j] * inv0); a1.v[j] = f2bf(s1[j] * inv1); }
    bf16x8 bv = *(const bf16x8*)(AwPk + (((size_t)(pb * 24 + kk)) << 9) + (lane << 3));
    acc[0] = mfma16(a0.f, bv, acc[0]);
    acc[1] = mfma16(a1.f, bv, acc[1]);
  }
#pragma unroll
  for (int mi = 0; mi < 2; ++mi)
#pragma unroll
    for (int r = 0; r < 4; ++r) {
      int row = mi * 16 + q * 4 + r;
      gpre[(size_t)row * D + nbase + t] = acc[mi][r];
    }
}

// ================= global kernels =================

__global__ void k_init(int* cnt, int* cursor, int* gcnt, float* pooled, float* xgacc,
                       const unsigned short* __restrict__ t,
                       const unsigned int* __restrict__ e, int* __restrict__ flags) {
  int i = blockIdx.x * 256 + threadIdx.x;
  if (i < NNODES) { cnt[i] = 0; cursor[i] = 0; }
  if (i < B) gcnt[i] = 0;
  if (i < B * D) { pooled[i] = 0.f; xgacc[i] = 0.f; }
  if (blockIdx.x == 0) {
    __shared__ int r0[256];
    __shared__ unsigned r1[256];
    int tid = threadIdx.x;
    int bad = 0;
    for (int j = tid; j < 8192; j += 256) {
      unsigned short u = t[2 * j];
      unsigned ex = (u >> 7) & 0xFF;
      if (ex >= 0xC0) bad = 1;
    }
    unsigned o = 0;
    for (int j = tid; j < NEDGES / 2; j += 256) o |= e[2 * j + 1];
    r0[tid] = bad; r1[tid] = o;
    __syncthreads();
    for (int s = 128; s > 0; s >>= 1) {
      if (tid < s) { r0[tid] |= r0[tid + s]; r1[tid] |= r1[tid + s]; }
      __syncthreads();
    }
    if (tid == 0) { flags[0] = r0[0]; flags[1] = (r1[0] == 0) ? 1 : 0; }
  }
}

// pack_in (0..1215) + wpack (1216..3231) + count (3232..3327); no LDS.
__global__ __launch_bounds__(256) void k_setup2(
    const void* x_in, unsigned short* x0, unsigned short* PkA,
    const void* text, unsigned short* Tpk,
    const void* Ws, const void* Wn, const void* Aw,
    unsigned short* WsPk, unsigned short* WnPk, unsigned short* AwPk,
    const void* edst, const void* batch, int* cnt, int* gcnt,
    const int* __restrict__ flags) {
  int bid = blockIdx.x, tid = threadIdx.x;
  if (bid < 1216) {
    int f = flags[0];
    if (bid < NNODES / 16) d_pack_in(x_in, x0, PkA, bid, tid, f);
    else d_pack_in(text, nullptr, Tpk, bid - NNODES / 16, tid, f);
  } else if (bid < 3232) {
    d_wpack(Ws, Wn, Aw, flags[0], WsPk, WnPk, AwPk, bid - 1216, tid);
  } else {
    d_count(edst, batch, flags[1], cnt, gcnt, (bid - 3232) * 256 + tid);
  }
}

__global__ void k_scan(const int* __restrict__ cnt, int* __restrict__ rowstart) {
  __shared__ int a[NNODES], b[NNODES];
  int tid = threadIdx.x;
  for (int i = tid; i < NNODES; i += 1024) a[i] = cnt[i];
  __syncthreads();
  int* s = a; int* d = b;
  for (int off = 1; off < NNODES; off <<= 1) {
    for (int i = tid; i < NNODES; i += 1024)
      d[i] = s[i] + (i >= off ? s[i - off] : 0);
    __syncthreads();
    int* t = s; s = d; d = t;
  }
  for (int i = tid; i < NNODES; i += 1024) rowstart[i + 1] = s[i];
  if (tid == 0) rowstart[0] = 0;
}

__global__ void k_scatter(const void* __restrict__ esrc, const void* __restrict__ edst,
                          const int* __restrict__ flags, const int* __restrict__ rowstart,
                          int* __restrict__ cursor, int* __restrict__ csr) {
  int w = flags[1];
  int i = blockIdx.x * 256 + threadIdx.x;
  if (i < NEDGES) {
    int dd = ldi(edst, i, w);
    int pos = atomicAdd(&cursor[dd], 1);
    csr[rowstart[dd] + pos] = ldi(esrc, i, w);
  }
}

__global__ __launch_bounds__(256) void k_msgp(
    const unsigned short* x, const int* cnt, const int* rowstart, const int* csr,
    unsigned short* Mpk) {
  d_msg(x, cnt, rowstart, csr, Mpk, blockIdx.x, threadIdx.x);
}

// XCD-bijective swizzles (grid%8==0 in both uses).
__device__ __forceinline__ void gemm_map(int g, int& bx, int& by) {
  int gs = (g % 8) * 72 + g / 8;   // 576 = 8*72; same-bx blocks land on one XCD
  bx = gs / 12; by = gs % 12;
}
__device__ __forceinline__ void sc_map(int g, int& bx, int& by, int& bz) {
  int gs = (g % 8) * 64 + g / 8;   // 512 = 8*64; same-bz blocks land on one XCD
  bx = gs & 1; by = (gs >> 1) & 7; bz = gs >> 4;
}

__global__ __launch_bounds__(256) void k_gemm(
    const unsigned short* Apk, const unsigned short* Mpk,
    const unsigned short* WsPk, const unsigned short* WnPk,
    const void* bias, unsigned long bias_off, const int* flags,
    unsigned short* Y, unsigned short* Ypk) {
  int bx, by; gemm_map(blockIdx.x, bx, by);
  d_gemm(Apk, Mpk, WsPk, WnPk, bias, bias_off, flags[0], Y, Ypk, bx, by, threadIdx.x);
}

// xp only (256 blocks) — pack stage deleted (gemm dual-writes packed).
__global__ __launch_bounds__(256) void k_postg(
    const unsigned short* Y, const void* pidx, const int* flags, const int* gcnt,
    unsigned short* xp, unsigned short* XpPk, float* xgacc) {
  extern __shared__ char smem[];
  d_xp(Y, pidx, flags[1], gcnt, xp, XpPk, xgacc, blockIdx.x, threadIdx.x, smem);
}

// msg(next) FIRST (0..msgN-1), then scores (msgN..msgN+511); no LDS.
__global__ __launch_bounds__(256) void k_scmsg(
    const unsigned short* XpPk, const unsigned short* Tpk, float* S,
    int msgN, const unsigned short* x, const int* cnt, const int* rowstart,
    const int* csr, unsigned short* Mpk) {
  int bid = blockIdx.x, tid = threadIdx.x;
  if (bid < msgN) d_msg(x, cnt, rowstart, csr, Mpk, bid, tid);
  else {
    int bx, by, bz; sc_map(bid - msgN, bx, by, bz);
    d_scores(XpPk, Tpk, S, bx, by, bz, tid);
  }
}

// gemm(next) FIRST (0..gemmN-1), then stats; 2KB smem used by stats only.
__global__ __launch_bounds__(256) void k_stgemm(
    const float* S, const int* gcnt, float* rmax, float* rsum, float* cmaxv, float* csumv,
    int gemmN, const unsigned short* Apk, const unsigned short* Mpk,
    const unsigned short* WsPk, const unsigned short* WnPk,
    const void* bias, unsigned long bias_off, const int* flags,
    unsigned short* Y, unsigned short* Ypk) {
  extern __shared__ char smem[];
  int bid = blockIdx.x, tid = threadIdx.x;
  if (bid < gemmN) {
    int bx, by; gemm_map(bid, bx, by);
    d_gemm(Apk, Mpk, WsPk, WnPk, bias, bias_off, flags[0], Y, Ypk, bx, by, tid);
  } else d_stats(S, gcnt, rmax, rsum, cmaxv, csumv, bid - gemmN, tid, smem);
}

// xp(next) FIRST (0..xpN-1), then cross.
__global__ __launch_bounds__(256) void k_crpostg(
    const float* S, const float* rmax, const float* rsum, const float* cmaxv,
    const float* csumv, const int* gcnt, float* wv, float* t2gcol,
    int xpN, const unsigned short* Y, const void* pidx, const int* flags,
    unsigned short* xp, unsigned short* XpPk, float* xgacc) {
  extern __shared__ char smem[];
  int bid = blockIdx.x, tid = threadIdx.x;
  if (bid < xpN) d_xp(Y, pidx, flags[1], gcnt, xp, XpPk, xgacc, bid, tid, smem);
  else d_cross(S, rmax, rsum, cmaxv, csumv, gcnt, wv, t2gcol, bid - xpN, tid, smem);
}

// msg FIRST (0..msgN-1), then scores(next) (scN), then pooled (320), then atom.
__global__ __launch_bounds__(256) void k_plscmsg(
    const float* wv, const float* t2gcol, const unsigned short* Tpk,
    const unsigned short* xpL, const int* gcnt, float* pooled,
    int msgN, const unsigned short* x, const int* cnt, const int* rowstart,
    const int* csr, unsigned short* Mpk,
    int scN, const unsigned short* XpPk, float* S,
    int atomN, const float* xgacc, const unsigned short* AwPk, float* gpre) {
  extern __shared__ char smem[];
  int bid = blockIdx.x, tid = threadIdx.x;
  if (bid < msgN) { d_msg(x, cnt, rowstart, csr, Mpk, bid, tid); return; }
  int r = bid - msgN;
  if (r < scN) {
    int bx, by, bz; sc_map(r, bx, by, bz);
    d_scores(XpPk, Tpk, S, bx, by, bz, tid); return;
  }
  r -= scN;
  if (r < 320) { d_pooled(wv, t2gcol, Tpk, xpL, gcnt, pooled, r, tid, smem); return; }
  d_atom(xgacc, gcnt, AwPk, gpre, r - 320, tid);
}

__global__ __launch_bounds__(256) void k_final(
    const unsigned short* __restrict__ Tpk, const float* __restrict__ gpre,
    const float* __restrict__ pooled, const void* __restrict__ ab,
    const void* __restrict__ dmask, const void* __restrict__ gmask,
    const void* __restrict__ remb, const int* __restrict__ flags,
    void* __restrict__ out) {
  int f = flags[0];
  int b = blockIdx.x, tid = threadIdx.x;
  float dm = ldf(dmask, b, f);
  float gm = ldf(gmask, b, f);
  float dg = dm * gm;
  size_t base = (size_t)b * 2304;
#pragma unroll
  for (int j = 0; j < 3; ++j) {
    int d = tid + j * 256;
    float z = ldf(remb, d, f);
    float tv = pk_read(Tpk, b * 32, 0, d);
    float o0 = tv * dm + (1.f - dm) * z;
    float gv = tanhf(gpre[(size_t)b * D + d] + ldf(ab, d, f));
    float o1 = gv * gm + (1.f - gm) * z;
    float p = pooled[(size_t)b * D + d] * (1.f / 3.f);
    float o2 = p * dg + (1.f - dg) * z;
    if (f) {
      float* of = (float*)out;
      of[base + d] = o0; of[base + 768 + d] = o1; of[base + 1536 + d] = o2;
    } else {
      unsigned short* ob = (unsigned short*)out;
      ob[base + d] = f2bf(o0); ob[base + 768 + d] = f2bf(o1); ob[base + 1536 + d] = f2bf(o2);
    }
  }
}

extern "C" void kernel_launch(void* const* d_in, const int* in_sizes, int n_in,
                              void* d_out, int out_size, void* d_ws, size_t ws_size,
                              hipStream_t stream) {
  const void* x_in  = d_in[0];
  const void* text  = d_in[1];
  const void* dmask = d_in[2];
  const void* gmask = d_in[3];
  const void* gws   = d_in[4];
  const void* gwn   = d_in[5];
  const void* gb    = d_in[6];
  const void* aw    = d_in[7];
  const void* ab    = d_in[8];
  const void* remb  = d_in[9];
  const void* batch = d_in[10];
  const void* pidx  = d_in[11];
  const void* esrc  = d_in[13];
  const void* edst  = d_in[14];

  char* wsp = (char*)d_ws;
  size_t off = 0;
  auto carve = [&](size_t bytes) -> void* {
    void* p = wsp + off;
    off += (bytes + 255) & ~(size_t)255;
    return p;
  };
  int* flags = (int*)carve(2 * 4);
  unsigned short* x0    = (unsigned short*)carve((size_t)NNODES * D * 2);
  unsigned short* xA    = (unsigned short*)carve((size_t)NNODES * D * 2);
  unsigned short* xB    = (unsigned short*)carve((size_t)NNODES * D * 2);
  unsigned short* PkA   = (unsigned short*)carve((size_t)NNODES * D * 2);
  unsigned short* PkB   = (unsigned short*)carve((size_t)NNODES * D * 2);
  unsigned short* Mpk   = (unsigned short*)carve((size_t)NNODES * D * 2);
  unsigned short* Tpk   = (unsigned short*)carve((size_t)B * L * D * 2);
  unsigned short* WsPk  = (unsigned short*)carve((size_t)3 * D * D * 2);
  unsigned short* WnPk  = (unsigned short*)carve((size_t)3 * D * D * 2);
  unsigned short* AwPk  = (unsigned short*)carve((size_t)D * D * 2);
  unsigned short* xpA   = (unsigned short*)carve((size_t)B * M * D * 2);
  unsigned short* xpB   = (unsigned short*)carve((size_t)B * M * D * 2);
  unsigned short* XpPkA = (unsigned short*)carve((size_t)B * M * D * 2);
  unsigned short* XpPkB = (unsigned short*)carve((size_t)B * M * D * 2);
  float* xgacc   = (float*)carve((size_t)B * D * 4);
  float* gpre    = (float*)carve((size_t)B * D * 4);
  float* S       = (float*)carve((size_t)B * M * L * 4);
  float* rmax    = (float*)carve((size_t)B * M * 4);
  float* rsum    = (float*)carve((size_t)B * M * 4);
  float* wv      = (float*)carve((size_t)B * L * 4);
  float* cmaxv   = (float*)carve((size_t)B * L * 4);
  float* csumv   = (float*)carve((size_t)B * L * 4);
  float* t2gcol  = (float*)carve((size_t)B * M * 4);
  float* pooled  = (float*)carve((size_t)B * D * 4);
  int* cnt      = (int*)carve((size_t)NNODES * 4);
  int* rowstart = (int*)carve((size_t)(NNODES + 1) * 4);
  int* cursor   = (int*)carve((size_t)NNODES * 4);
  int* gcnt     = (int*)carve((size_t)B * 4);
  int* csr      = (int*)carve((size_t)NEDGES * 4);

  const size_t DD = (size_t)D * D;

  k_init<<<96, 256, 0, stream>>>(cnt, cursor, gcnt, pooled, xgacc,
                                 (const unsigned short*)text, (const unsigned int*)edst, flags);
  k_setup2<<<3328, 256, 0, stream>>>(x_in, x0, PkA, text, Tpk, gws, gwn, aw,
                                     WsPk, WnPk, AwPk, edst, batch, cnt, gcnt, flags);
  k_scan<<<1, 1024, 0, stream>>>(cnt, rowstart);
  k_scatter<<<96, 256, 0, stream>>>(esrc, edst, flags, rowstart, cursor, csr);

  // ---- pipelined layer schedule ----
  k_msgp<<<192, 256, 0, stream>>>(x0, cnt, rowstart, csr, Mpk);
  k_gemm<<<576, 256, 0, stream>>>(PkA, Mpk, WsPk, WnPk, gb, 0, flags, xA, PkB);
  k_postg<<<256, 256, 24832, stream>>>(xA, pidx, flags, gcnt, xpA, XpPkA, nullptr);
  k_scmsg<<<704, 256, 0, stream>>>(XpPkA, Tpk, S, 192, xA, cnt, rowstart, csr, Mpk);
  k_stgemm<<<4928, 256, 2048, stream>>>(S, gcnt, rmax, rsum, cmaxv, csumv,
                                        576, PkB, Mpk, WsPk + DD, WnPk + DD, gb, D, flags,
                                        xB, PkA);
  k_crpostg<<<4608, 256, 24832, stream>>>(S, rmax, rsum, cmaxv, csumv, gcnt, wv, t2gcol,
                                          256, xB, pidx, flags, xpB, XpPkB, nullptr);
  k_plscmsg<<<1024, 256, 4096, stream>>>(wv, t2gcol, Tpk, xpA, gcnt, pooled,
                                         192, xB, cnt, rowstart, csr, Mpk,
                                         512, XpPkB, S,
                                         0, nullptr, nullptr, nullptr);
  k_stgemm<<<4928, 256, 2048, stream>>>(S, gcnt, rmax, rsum, cmaxv, csumv,
                                        576, PkA, Mpk, WsPk + 2 * DD, WnPk + 2 * DD,
                                        gb, 2 * D, flags, xA, nullptr);
  k_crpostg<<<4608, 256, 24832, stream>>>(S, rmax, rsum, cmaxv, csumv, gcnt, wv, t2gcol,
                                          256, xA, pidx, flags, xpA, XpPkA, xgacc);
  k_plscmsg<<<832, 256, 4096, stream>>>(wv, t2gcol, Tpk, xpB, gcnt, pooled,
                                        0, nullptr, nullptr, nullptr, nullptr, nullptr,
                                        512, XpPkA, S,
                                        0, nullptr, nullptr, nullptr);
  k_stgemm<<<4352, 256, 2048, stream>>>(S, gcnt, rmax, rsum, cmaxv, csumv,
                                        0, nullptr, nullptr, nullptr, nullptr,
                                        nullptr, 0, flags, nullptr, nullptr);
  k_crpostg<<<4352, 256, 2048, stream>>>(S, rmax, rsum, cmaxv, csumv, gcnt, wv, t2gcol,
                                         0, nullptr, pidx, flags, nullptr, nullptr, nullptr);
  k_plscmsg<<<332, 256, 4096, stream>>>(wv, t2gcol, Tpk, xpA, gcnt, pooled,
                                        0, nullptr, nullptr, nullptr, nullptr, nullptr,
                                        0, nullptr, nullptr,
                                        12, xgacc, AwPk, gpre);
  k_final<<<32, 256, 0, stream>>>(Tpk, gpre, pooled, ab, dmask, gmask, remb, flags, d_out);
}